// Round 15
// baseline (432.854 us; speedup 1.0000x reference)
//
#include <hip/hip_runtime.h>
#include <math.h>

// Problem constants
#define BB 2
#define DD 128
#define LL 2048
#define HH 8
#define OC 1024     // H*D
#define RR_ 128
#define BL (BB*LL)          // 4096
#define NROW (BL*HH)        // 32768
#define XROWS 2052

// Numerics ledger (absmax bf16-quantized; threshold 180.48):
//   r3 full fp64 -> 128 PASS | r2 seq fp32 (~7e-7) -> 192 FAIL
//   r5 chunk32+tanhf (~5e-7) -> 192 FAIL | r6 chunk4/8+fp64 tanh -> 128 PASS
//   r7-r11 MFMA ladder -> 64 PASS | r12/r13 fast tanh -> FAIL (mistyped
//   constant C, 8.5e-5 rel arg error) | r14 fixed C -> 64 PASS, 268us.
// r15: structure only — conv block batches 4 o-tiles per x-staging
//      (grid.y 48->12, staging redundancy 48x->12x, 4x MFMA per barrier,
//      768 blocks = exactly 3/CU). Per-element arithmetic bit-identical.

typedef __bf16  bf16x8  __attribute__((ext_vector_type(8)));
typedef float   float4v __attribute__((ext_vector_type(4)));

__device__ __forceinline__ void enc2(const float* src, bf16x8& p1, bf16x8& p2) {
    #pragma unroll
    for (int j = 0; j < 8; ++j) {
        float v = src[j];
        __bf16 h1 = (__bf16)v;
        p1[j] = h1;
        p2[j] = (__bf16)(v - (float)h1);
    }
}

// phi = SR*tanh(u1*u2/SR) = SR*(1 - 2/(2^y + 1)), y = u1*u2*(2/sqrt(128))*log2e.
// fp64 pipeline; exp2 core: n = rint(y), f = y-n in [-0.5,0.5];
// 2^f = 1 + c1*f + f^2*(c2 + f*Q32(f)), Q32 = c3..c9 Horner in fp32;
// 2^n by exponent bits; reciprocal = v_rcp_f32 seed + 2 fp64 Newton steps.
__device__ __forceinline__ float fast_phi(double u1, double u2) {
    const double TWO_ISR = 0.17677669529663688110;  // 2/sqrt(128) = sqrt(2)/8
    const double LOG2E   = 1.44269504088896340736;  // log2(e)
    const double SR      = 11.313708498984760390;   // sqrt(128)
    double y = (u1*u2) * (TWO_ISR * LOG2E);
    y = fmin(fmax(y, -1020.4), 1020.4);
    double n = rint(y);
    double f = y - n;
    float ff = (float)f;
    float q;
    q = fmaf(1.01780860092396960e-7f, ff, 1.32154867901443094e-6f);
    q = fmaf(q, ff, 1.52527338040598403e-5f);
    q = fmaf(q, ff, 1.54035303933816099e-4f);
    q = fmaf(q, ff, 1.33335581464284434e-3f);
    q = fmaf(q, ff, 9.61812910762847716e-3f);
    q = fmaf(q, ff, 5.55041086648215800e-2f);
    double t2   = fma(f, (double)q, 0.24022650695910071233);
    double head = fma(f, 0.69314718055994530942, 1.0);
    double E0   = fma(f*f, t2, head);
    int ni = (int)n;
    double En = __hiloint2double((ni + 1023) << 20, 0);   // 2^n
    double E  = E0 * En;
    double den = E + 1.0;
    double r = (double)__builtin_amdgcn_rcpf((float)den);
    r = r * fma(-den, r, 2.0);
    r = r * fma(-den, r, 2.0);
    double t = fma(-2.0, r, 1.0);
    return (float)(SR * t);
}

// ---------------------------------------------------------------------------
// Kernel 0: fused encode (weights + x). (r11-proven)
// ---------------------------------------------------------------------------
__global__ __launch_bounds__(256) void enc_fused_k(
    const float* __restrict__ q_w, const float* __restrict__ k_w,
    const float* __restrict__ v_w, const float* __restrict__ pw,
    const float* __restrict__ g1_q, const float* __restrict__ g2_q,
    const float* __restrict__ g1_k, const float* __restrict__ g2_k,
    const float* __restrict__ x,
    __bf16* __restrict__ wenc, __bf16* __restrict__ genc,
    __bf16* __restrict__ venc, __bf16* __restrict__ penc,
    __bf16* __restrict__ xenc)
{
    __shared__ float t[32][33];
    const int bid = blockIdx.x;
    const int tid = threadIdx.x;
    if (bid < 2304) {
        const int gid = bid*256 + tid;
        if (gid < 262144) {
            const int o = gid >> 7, c = gid & 127;
            #pragma unroll
            for (int tt = 0; tt < 3; ++tt) {
                float v = (o < 1024) ? q_w[(o*128 + c)*3 + tt]
                                     : k_w[((o-1024)*128 + c)*3 + tt];
                __bf16 h1 = (__bf16)v;  float r1 = v - (float)h1;
                __bf16 h2 = (__bf16)r1; float r2 = r1 - (float)h2;
                __bf16 h3 = (__bf16)r2;
                wenc[((size_t)(0*3 + tt)*2048 + o)*128 + c] = h1;
                wenc[((size_t)(1*3 + tt)*2048 + o)*128 + c] = h2;
                wenc[((size_t)(2*3 + tt)*2048 + o)*128 + c] = h3;
            }
        } else if (gid < 262144 + 65536) {
            const int g = gid - 262144;
            const int mat = g >> 14, rem = g & 16383;
            const int r = rem >> 7, d = rem & 127;
            const float* src = (mat == 0) ? g1_q : (mat == 1) ? g2_q
                             : (mat == 2) ? g1_k : g2_k;
            float v = src[d*RR_ + r];
            __bf16 h1 = (__bf16)v;  float r1 = v - (float)h1;
            __bf16 h2 = (__bf16)r1; float r2 = r1 - (float)h2;
            __bf16 h3 = (__bf16)r2;
            genc[((size_t)(mat*3 + 0)*128 + r)*128 + d] = h1;
            genc[((size_t)(mat*3 + 1)*128 + r)*128 + d] = h2;
            genc[((size_t)(mat*3 + 2)*128 + r)*128 + d] = h3;
        } else if (gid < 262144 + 65536 + 131072) {
            const int g = gid - 262144 - 65536;
            const int o = g >> 7, c = g & 127;
            float v = v_w[o*128 + c];
            __bf16 h1 = (__bf16)v;  float r1 = v - (float)h1;
            __bf16 h2 = (__bf16)r1;
            venc[((size_t)0*1024 + o)*128 + c] = h1;
            venc[((size_t)1*1024 + o)*128 + c] = h2;
        } else if (gid < 262144 + 65536 + 131072 + 131072) {
            const int g = gid - 262144 - 65536 - 131072;
            const int j = g >> 10, k = g & 1023;
            float v = pw[(size_t)j*OC + k];
            __bf16 h1 = (__bf16)v;  float r1 = v - (float)h1;
            __bf16 h2 = (__bf16)r1;
            penc[((size_t)(0*128 + j))*OC + k] = h1;
            penc[((size_t)(1*128 + j))*OC + k] = h2;
        }
    } else {
        const int g = bid - 2304;
        const int lt = g & 63, ct = (g >> 6) & 3, b = g >> 8;
        const int l0 = lt*32, c0 = ct*32;
        for (int e = tid; e < 32*32; e += 256) {
            int c = e >> 5, l = e & 31;
            t[c][l] = x[((size_t)(b*DD + c0 + c))*LL + l0 + l];
        }
        __syncthreads();
        for (int e = tid; e < 32*32; e += 256) {
            int l = e >> 5, c = e & 31;
            float v = t[c][l];
            __bf16 h1 = (__bf16)v;  float r1 = v - (float)h1;
            __bf16 h2 = (__bf16)r1; float r2 = r1 - (float)h2;
            __bf16 h3 = (__bf16)r2;
            const size_t row = (size_t)(l0 + l + 2);
            xenc[((size_t)(0*2 + b)*XROWS + row)*128 + c0 + c] = h1;
            xenc[((size_t)(1*2 + b)*XROWS + row)*128 + c0 + c] = h2;
            xenc[((size_t)(2*2 + b)*XROWS + row)*128 + c0 + c] = h3;
        }
        if (lt == 0 && ct == 0) {
            for (int e = tid; e < 2*128; e += 256) {
                int row = e >> 7, c = e & 127;
                xenc[((size_t)(0*2 + b)*XROWS + row)*128 + c] = (__bf16)0.f;
                xenc[((size_t)(1*2 + b)*XROWS + row)*128 + c] = (__bf16)0.f;
                xenc[((size_t)(2*2 + b)*XROWS + row)*128 + c] = (__bf16)0.f;
            }
        }
    }
}

// ---------------------------------------------------------------------------
// Kernel 1: fused q+k conv (3-plane/6-pass) AND v (2-plane/4-pass).
// r15: 4 o-tiles per block off one x-staging. grid (64, 12):
//   y 0..7  -> conv o-tiles y*4..y*4+3 (q for y<4, k for y>=4)
//   y 8..11 -> v o-tiles (y-8)*4..(y-8)*4+3
// ---------------------------------------------------------------------------
__global__ __launch_bounds__(256) void conv_mfma_k(
    const __bf16* __restrict__ xenc, const __bf16* __restrict__ wenc,
    const __bf16* __restrict__ venc,
    const float* __restrict__ q_b, const float* __restrict__ k_b,
    const float* __restrict__ gamma_q, const float* __restrict__ beta_q,
    const float* __restrict__ gamma_k, const float* __restrict__ beta_k,
    float* __restrict__ q_s, float* __restrict__ k_s, float* __restrict__ v_s)
{
    __shared__ __bf16 As[3][66][136];
    const int tid  = threadIdx.x;
    const int wave = tid >> 6;
    const int lane = tid & 63;
    const int m    = lane & 15;
    const int quad = lane >> 4;
    const int bx = blockIdx.x;
    const int b  = bx >> 5;
    const int lb0 = (bx & 31) << 6;
    const int yt = blockIdx.y;

    for (int e = tid; e < 3*66*16; e += 256) {
        const int p = e / (66*16), rem = e % (66*16);
        const int row = rem >> 4, cg = rem & 15;
        *(bf16x8*)&As[p][row][cg*8] =
            *(const bf16x8*)&xenc[((size_t)(p*2 + b)*XROWS + lb0 + row)*128 + cg*8];
    }
    __syncthreads();

    if (yt < 8) {
        #pragma unroll 1
        for (int ot = 0; ot < 4; ++ot) {
            const int o0 = (yt*4 + ot) << 6;
            const int osub = o0 + wave*16;
            float4v accm[4][4];
            float4v corr[4][2];
            #pragma unroll
            for (int lt = 0; lt < 4; ++lt) {
                corr[lt][0] = (float4v){0.f,0.f,0.f,0.f};
                corr[lt][1] = (float4v){0.f,0.f,0.f,0.f};
                #pragma unroll
                for (int c = 0; c < 4; ++c) accm[lt][c] = (float4v){0.f,0.f,0.f,0.f};
            }
            #pragma unroll
            for (int cidx = 0; cidx < 4; ++cidx) {
                const int c0 = cidx << 5;
                #pragma unroll
                for (int t = 0; t < 3; ++t) {
                    bf16x8 B1, B2, B3;
                    {
                        size_t base = ((size_t)t*2048 + osub + m)*128 + c0 + quad*8;
                        B1 = *(const bf16x8*)&wenc[base];
                        B2 = *(const bf16x8*)&wenc[base + (size_t)3*2048*128];
                        B3 = *(const bf16x8*)&wenc[base + (size_t)6*2048*128];
                    }
                    #pragma unroll
                    for (int lt = 0; lt < 4; ++lt) {
                        const int row = lt*16 + m + t;
                        bf16x8 A1 = *(const bf16x8*)&As[0][row][c0 + quad*8];
                        bf16x8 A2 = *(const bf16x8*)&As[1][row][c0 + quad*8];
                        bf16x8 A3 = *(const bf16x8*)&As[2][row][c0 + quad*8];
                        accm[lt][cidx] = __builtin_amdgcn_mfma_f32_16x16x32_bf16(A1, B1, accm[lt][cidx], 0, 0, 0);
                        corr[lt][0] = __builtin_amdgcn_mfma_f32_16x16x32_bf16(A1, B2, corr[lt][0], 0, 0, 0);
                        corr[lt][1] = __builtin_amdgcn_mfma_f32_16x16x32_bf16(A2, B1, corr[lt][1], 0, 0, 0);
                        corr[lt][0] = __builtin_amdgcn_mfma_f32_16x16x32_bf16(A1, B3, corr[lt][0], 0, 0, 0);
                        corr[lt][1] = __builtin_amdgcn_mfma_f32_16x16x32_bf16(A3, B1, corr[lt][1], 0, 0, 0);
                        corr[lt][0] = __builtin_amdgcn_mfma_f32_16x16x32_bf16(A2, B2, corr[lt][0], 0, 0, 0);
                    }
                }
            }
            const int is_k = (o0 >= 1024);
            const double g  = (double)(is_k ? gamma_k[0] : gamma_q[0]);
            const double be = (double)(is_k ? beta_k[0]  : beta_q[0]);
            const int o_global = osub + m;
            const int o_local  = o_global - (is_k ? 1024 : 0);
            const double bias  = (double)(is_k ? k_b[o_local] : q_b[o_local]);
            float* dest = is_k ? k_s : q_s;
            #pragma unroll
            for (int lt = 0; lt < 4; ++lt) {
                #pragma unroll
                for (int reg = 0; reg < 4; ++reg) {
                    double s = (double)corr[lt][0][reg] + (double)corr[lt][1][reg];
                    #pragma unroll
                    for (int c = 0; c < 4; ++c) s += (double)accm[lt][c][reg];
                    const int l = lb0 + lt*16 + quad*4 + reg;
                    dest[((size_t)(b*LL + l))*OC + o_local] = (float)(g*(s + bias) + be);
                }
            }
        }
    } else {
        #pragma unroll 1
        for (int ot = 0; ot < 4; ++ot) {
            const int o0 = ((yt - 8)*4 + ot) << 6;
            const int osub = o0 + wave*16;
            float4v accm[4][4];
            float4v corr[4];
            #pragma unroll
            for (int lt = 0; lt < 4; ++lt) {
                corr[lt] = (float4v){0.f,0.f,0.f,0.f};
                #pragma unroll
                for (int c = 0; c < 4; ++c) accm[lt][c] = (float4v){0.f,0.f,0.f,0.f};
            }
            #pragma unroll
            for (int cidx = 0; cidx < 4; ++cidx) {
                const int c0 = cidx << 5;
                bf16x8 B1, B2;
                {
                    size_t base = ((size_t)(osub + m))*128 + c0 + quad*8;
                    B1 = *(const bf16x8*)&venc[base];
                    B2 = *(const bf16x8*)&venc[base + (size_t)1024*128];
                }
                #pragma unroll
                for (int lt = 0; lt < 4; ++lt) {
                    const int row = lt*16 + m + 2;
                    bf16x8 A1 = *(const bf16x8*)&As[0][row][c0 + quad*8];
                    bf16x8 A2 = *(const bf16x8*)&As[1][row][c0 + quad*8];
                    accm[lt][cidx] = __builtin_amdgcn_mfma_f32_16x16x32_bf16(A1, B1, accm[lt][cidx], 0, 0, 0);
                    corr[lt] = __builtin_amdgcn_mfma_f32_16x16x32_bf16(A1, B2, corr[lt], 0, 0, 0);
                    corr[lt] = __builtin_amdgcn_mfma_f32_16x16x32_bf16(A2, B1, corr[lt], 0, 0, 0);
                    corr[lt] = __builtin_amdgcn_mfma_f32_16x16x32_bf16(A2, B2, corr[lt], 0, 0, 0);
                }
            }
            const int o_local = osub + m;
            #pragma unroll
            for (int lt = 0; lt < 4; ++lt) {
                #pragma unroll
                for (int reg = 0; reg < 4; ++reg) {
                    float s = corr[lt][reg];
                    #pragma unroll
                    for (int c = 0; c < 4; ++c) s += accm[lt][c][reg];
                    const int l = lb0 + lt*16 + quad*4 + reg;
                    v_s[((size_t)(b*LL + l))*OC + o_local] = s;
                }
            }
        }
    }
}

// ---------------------------------------------------------------------------
// Kernel 2: sketch q+k fused, 3-plane/6-pass MFMA in-place; fast_phi epilogue.
// ---------------------------------------------------------------------------
__global__ __launch_bounds__(256) void sketch_mfma_k(
    float* __restrict__ q_s, float* __restrict__ k_s,
    const __bf16* __restrict__ genc_all)
{
    __shared__ __bf16 As[3][32][136];
    const int tid  = threadIdx.x;
    const int wave = tid >> 6;
    const int lane = tid & 63;
    const int m    = lane & 15;
    const int quad = lane >> 4;
    const int half = blockIdx.x >> 10;
    float* buf = half ? k_s : q_s;
    const __bf16* genc = genc_all + (size_t)half*2*3*128*128;
    const size_t i0 = (size_t)(blockIdx.x & 1023) * 32;

    for (int e = tid; e < 32*128; e += 256) {
        int row = e >> 7, d = e & 127;
        float v = buf[(i0 + row)*RR_ + d];
        __bf16 h1 = (__bf16)v;  float r1 = v - (float)h1;
        __bf16 h2 = (__bf16)r1; float r2 = r1 - (float)h2;
        __bf16 h3 = (__bf16)r2;
        As[0][row][d] = h1; As[1][row][d] = h2; As[2][row][d] = h3;
    }
    __syncthreads();

    float4v accm[2][2][2], corr[2][2][2];
    #pragma unroll
    for (int mt = 0; mt < 2; ++mt)
        #pragma unroll
        for (int nt = 0; nt < 2; ++nt)
            #pragma unroll
            for (int mat = 0; mat < 2; ++mat) {
                accm[mt][nt][mat] = (float4v){0.f,0.f,0.f,0.f};
                corr[mt][nt][mat] = (float4v){0.f,0.f,0.f,0.f};
            }

    #pragma unroll
    for (int ck = 0; ck < 4; ++ck) {
        const int k0 = ck << 5;
        bf16x8 A1[2], A2[2], A3[2];
        #pragma unroll
        for (int mt = 0; mt < 2; ++mt) {
            A1[mt] = *(const bf16x8*)&As[0][mt*16 + m][k0 + quad*8];
            A2[mt] = *(const bf16x8*)&As[1][mt*16 + m][k0 + quad*8];
            A3[mt] = *(const bf16x8*)&As[2][mt*16 + m][k0 + quad*8];
        }
        #pragma unroll
        for (int nt = 0; nt < 2; ++nt) {
            const int r = wave*32 + nt*16 + m;
            #pragma unroll
            for (int mat = 0; mat < 2; ++mat) {
                size_t base = ((size_t)(mat*3)*128 + r)*128 + k0 + quad*8;
                bf16x8 B1 = *(const bf16x8*)&genc[base];
                bf16x8 B2 = *(const bf16x8*)&genc[base + (size_t)128*128];
                bf16x8 B3 = *(const bf16x8*)&genc[base + (size_t)2*128*128];
                #pragma unroll
                for (int mt = 0; mt < 2; ++mt) {
                    accm[mt][nt][mat] = __builtin_amdgcn_mfma_f32_16x16x32_bf16(A1[mt], B1, accm[mt][nt][mat], 0, 0, 0);
                    corr[mt][nt][mat] = __builtin_amdgcn_mfma_f32_16x16x32_bf16(A1[mt], B2, corr[mt][nt][mat], 0, 0, 0);
                    corr[mt][nt][mat] = __builtin_amdgcn_mfma_f32_16x16x32_bf16(A2[mt], B1, corr[mt][nt][mat], 0, 0, 0);
                    corr[mt][nt][mat] = __builtin_amdgcn_mfma_f32_16x16x32_bf16(A1[mt], B3, corr[mt][nt][mat], 0, 0, 0);
                    corr[mt][nt][mat] = __builtin_amdgcn_mfma_f32_16x16x32_bf16(A3[mt], B1, corr[mt][nt][mat], 0, 0, 0);
                    corr[mt][nt][mat] = __builtin_amdgcn_mfma_f32_16x16x32_bf16(A2[mt], B2, corr[mt][nt][mat], 0, 0, 0);
                }
            }
        }
    }
    __syncthreads();

    #pragma unroll
    for (int mt = 0; mt < 2; ++mt)
        #pragma unroll
        for (int nt = 0; nt < 2; ++nt)
            #pragma unroll
            for (int reg = 0; reg < 4; ++reg) {
                double u1 = (double)accm[mt][nt][0][reg] + (double)corr[mt][nt][0][reg];
                double u2 = (double)accm[mt][nt][1][reg] + (double)corr[mt][nt][1][reg];
                const size_t row = i0 + mt*16 + quad*4 + reg;
                const int col = wave*32 + nt*16 + m;
                buf[row*RR_ + col] = fast_phi(u1, u2);
            }
}

// ---------------------------------------------------------------------------
// Kernel 3: KV^T partials via 2-plane MFMA + fp64 Ksum partials (r10-proven).
// ---------------------------------------------------------------------------
__global__ __launch_bounds__(512) void kv_mfma_k(
    const float* __restrict__ phi_k, const float* __restrict__ v,
    float* __restrict__ part_kv, double* __restrict__ part_ks)
{
    __shared__ float Pt[128*36];
    __shared__ float Vt[128*36];
    __shared__ double ksred[512];
    const int tid  = threadIdx.x;
    const int wave = tid >> 6;
    const int lane = tid & 63;
    const int m    = lane & 15;
    const int quad = lane >> 4;
    const int split = blockIdx.x;
    const int bh    = blockIdx.y;
    const int b = bh >> 3, h = bh & 7;
    const int lbase = split * 128;
    const int dh = wave & 1;
    const int rq = wave >> 1;

    float4v accm[4][2], corr[4][2];
    #pragma unroll
    for (int mt = 0; mt < 4; ++mt)
        #pragma unroll
        for (int nt = 0; nt < 2; ++nt) {
            accm[mt][nt] = (float4v){0.f,0.f,0.f,0.f};
            corr[mt][nt] = (float4v){0.f,0.f,0.f,0.f};
        }
    double ks = 0.0;

    for (int ch = 0; ch < 4; ++ch) {
        __syncthreads();
        for (int e = tid; e < 32*128; e += 512) {
            const int l = e >> 7, r = e & 127;
            size_t base = ((size_t)(b*LL + lbase + ch*32 + l)*HH + h)*RR_;
            float pv = phi_k[base + r];
            float vv = v[base + r];
            Pt[r*36 + l] = pv;
            Vt[r*36 + l] = vv;
            ks += (double)pv;
        }
        __syncthreads();
        bf16x8 A1[4], A2[4], B1[2], B2[2];
        #pragma unroll
        for (int mt = 0; mt < 4; ++mt)
            enc2(&Vt[(dh*64 + mt*16 + m)*36 + quad*8], A1[mt], A2[mt]);
        #pragma unroll
        for (int nt = 0; nt < 2; ++nt)
            enc2(&Pt[(rq*32 + nt*16 + m)*36 + quad*8], B1[nt], B2[nt]);
        #pragma unroll
        for (int mt = 0; mt < 4; ++mt)
            #pragma unroll
            for (int nt = 0; nt < 2; ++nt) {
                accm[mt][nt] = __builtin_amdgcn_mfma_f32_16x16x32_bf16(A1[mt], B1[nt], accm[mt][nt], 0, 0, 0);
                corr[mt][nt] = __builtin_amdgcn_mfma_f32_16x16x32_bf16(A1[mt], B2[nt], corr[mt][nt], 0, 0, 0);
                corr[mt][nt] = __builtin_amdgcn_mfma_f32_16x16x32_bf16(A2[mt], B1[nt], corr[mt][nt], 0, 0, 0);
                corr[mt][nt] = __builtin_amdgcn_mfma_f32_16x16x32_bf16(A2[mt], B2[nt], corr[mt][nt], 0, 0, 0);
            }
    }

    ksred[tid] = ks;
    __syncthreads();
    if (tid < 128) {
        double s = ksred[tid] + ksred[tid+128] + ksred[tid+256] + ksred[tid+384];
        part_ks[(bh*16 + split)*RR_ + tid] = s;
    }

    float* outp = part_kv + ((size_t)(bh*16 + split))*RR_*DD;
    #pragma unroll
    for (int mt = 0; mt < 4; ++mt)
        #pragma unroll
        for (int nt = 0; nt < 2; ++nt)
            #pragma unroll
            for (int reg = 0; reg < 4; ++reg) {
                const int d = dh*64 + mt*16 + quad*4 + reg;
                const int r = rq*32 + nt*16 + m;
                outp[d*128 + r] = accm[mt][nt][reg] + corr[mt][nt][reg];
            }
}

// ---------------------------------------------------------------------------
// Kernel 4: reduce KVT partials -> bf16 2-plane KVTenc.
// ---------------------------------------------------------------------------
__global__ __launch_bounds__(256) void kvreduce_k(
    const float* __restrict__ part_kv, __bf16* __restrict__ kvt_enc)
{
    const int gid = blockIdx.x*256 + threadIdx.x;
    if (gid >= 16*RR_*DD) return;
    const int bh = gid >> 14;
    const int rd = gid & 16383;
    float s = 0.f;
    #pragma unroll
    for (int c = 0; c < 16; ++c)
        s += part_kv[(((size_t)(bh*16 + c)) << 14) + rd];
    __bf16 h1 = (__bf16)s;
    __bf16 h2 = (__bf16)(s - (float)h1);
    kvt_enc[(size_t)bh*16384 + rd] = h1;
    kvt_enc[(size_t)(16 + bh)*16384 + rd] = h2;
}

// ---------------------------------------------------------------------------
// Kernel 5: numerator MFMA + fp64 den (r10-proven).
// ---------------------------------------------------------------------------
__global__ __launch_bounds__(256) void numden_mfma_k(
    const float* __restrict__ phi_q, const __bf16* __restrict__ kvt_enc,
    const double* __restrict__ part_ks, float* __restrict__ o_out)
{
    __shared__ float Pq[64*132];
    __shared__ double Ks_s[128];
    __shared__ double den_s[64];
    const int tid  = threadIdx.x;
    const int wave = tid >> 6;
    const int lane = tid & 63;
    const int m    = lane & 15;
    const int quad = lane >> 4;
    const int lt = blockIdx.x;
    const int bh = blockIdx.y;
    const int b = bh >> 3, h = bh & 7;
    const int l0 = lt * 64;

    if (tid < 128) {
        double s = 0.0;
        #pragma unroll
        for (int c = 0; c < 16; ++c) s += part_ks[(bh*16 + c)*RR_ + tid];
        Ks_s[tid] = s;
    }
    for (int e = tid; e < 64*128; e += 256) {
        const int l = e >> 7, r = e & 127;
        Pq[l*132 + r] = phi_q[((size_t)(b*LL + l0 + l)*HH + h)*RR_ + r];
    }
    __syncthreads();

    double den = 0.0;
    if (tid < 64) {
        #pragma unroll
        for (int r = 0; r < 128; ++r)
            den += (double)Pq[tid*132 + r] * Ks_s[r];
    }

    float4v accm[4][2], corr[4][2];
    #pragma unroll
    for (int mt = 0; mt < 4; ++mt)
        #pragma unroll
        for (int nt = 0; nt < 2; ++nt) {
            accm[mt][nt] = (float4v){0.f,0.f,0.f,0.f};
            corr[mt][nt] = (float4v){0.f,0.f,0.f,0.f};
        }

    #pragma unroll
    for (int ck = 0; ck < 4; ++ck) {
        const int k0 = ck << 5;
        bf16x8 A1[4], A2[4];
        #pragma unroll
        for (int mt = 0; mt < 4; ++mt)
            enc2(&Pq[(mt*16 + m)*132 + k0 + quad*8], A1[mt], A2[mt]);
        #pragma unroll
        for (int nt = 0; nt < 2; ++nt) {
            const int d = wave*32 + nt*16 + m;
            size_t base = ((size_t)bh*128 + d)*128 + k0 + quad*8;
            bf16x8 B1 = *(const bf16x8*)&kvt_enc[base];
            bf16x8 B2 = *(const bf16x8*)&kvt_enc[base + (size_t)16*16384];
            #pragma unroll
            for (int mt = 0; mt < 4; ++mt) {
                accm[mt][nt] = __builtin_amdgcn_mfma_f32_16x16x32_bf16(A1[mt], B1, accm[mt][nt], 0, 0, 0);
                corr[mt][nt] = __builtin_amdgcn_mfma_f32_16x16x32_bf16(A1[mt], B2, corr[mt][nt], 0, 0, 0);
                corr[mt][nt] = __builtin_amdgcn_mfma_f32_16x16x32_bf16(A2[mt], B1, corr[mt][nt], 0, 0, 0);
                corr[mt][nt] = __builtin_amdgcn_mfma_f32_16x16x32_bf16(A2[mt], B2, corr[mt][nt], 0, 0, 0);
            }
        }
    }

    __syncthreads();
    if (tid < 64) den_s[tid] = den;
    __syncthreads();

    #pragma unroll
    for (int mt = 0; mt < 4; ++mt)
        #pragma unroll
        for (int nt = 0; nt < 2; ++nt)
            #pragma unroll
            for (int reg = 0; reg < 4; ++reg) {
                const int ll = mt*16 + quad*4 + reg;
                const int d  = wave*32 + nt*16 + m;
                const float inv = (float)(1.0 / (den_s[ll] + 1e-6));
                o_out[((size_t)(b*LL + l0 + ll))*OC + h*DD + d] =
                    (accm[mt][nt][reg] + corr[mt][nt][reg]) * inv;
            }
}

// ---------------------------------------------------------------------------
// Kernel 6: output projection partials via 2-plane MFMA (r10-proven).
// ---------------------------------------------------------------------------
__global__ __launch_bounds__(256) void proj_part_mfma_k(
    const float* __restrict__ o_s, const __bf16* __restrict__ penc,
    float* __restrict__ part)
{
    __shared__ float As[32*260];
    const int tid  = threadIdx.x;
    const int wave = tid >> 6;
    const int lane = tid & 63;
    const int m    = lane & 15;
    const int quad = lane >> 4;
    const int row0  = blockIdx.x * 32;
    const int kbase = blockIdx.y * 256;

    for (int e = tid; e < 32*256; e += 256) {
        const int row = e >> 8, k = e & 255;
        As[row*260 + k] = o_s[(size_t)(row0 + row)*OC + kbase + k];
    }
    __syncthreads();

    float4v accm[2][2], corr[2][2];
    #pragma unroll
    for (int mt = 0; mt < 2; ++mt)
        #pragma unroll
        for (int nt = 0; nt < 2; ++nt) {
            accm[mt][nt] = (float4v){0.f,0.f,0.f,0.f};
            corr[mt][nt] = (float4v){0.f,0.f,0.f,0.f};
        }

    #pragma unroll
    for (int ck = 0; ck < 8; ++ck) {
        const int k0 = ck << 5;
        bf16x8 A1[2], A2[2];
        #pragma unroll
        for (int mt = 0; mt < 2; ++mt)
            enc2(&As[(mt*16 + m)*260 + k0 + quad*8], A1[mt], A2[mt]);
        #pragma unroll
        for (int nt = 0; nt < 2; ++nt) {
            const int j = wave*32 + nt*16 + m;
            size_t base = ((size_t)j)*OC + kbase + k0 + quad*8;
            bf16x8 B1 = *(const bf16x8*)&penc[base];
            bf16x8 B2 = *(const bf16x8*)&penc[base + (size_t)128*OC];
            #pragma unroll
            for (int mt = 0; mt < 2; ++mt) {
                accm[mt][nt] = __builtin_amdgcn_mfma_f32_16x16x32_bf16(A1[mt], B1, accm[mt][nt], 0, 0, 0);
                corr[mt][nt] = __builtin_amdgcn_mfma_f32_16x16x32_bf16(A1[mt], B2, corr[mt][nt], 0, 0, 0);
                corr[mt][nt] = __builtin_amdgcn_mfma_f32_16x16x32_bf16(A2[mt], B1, corr[mt][nt], 0, 0, 0);
                corr[mt][nt] = __builtin_amdgcn_mfma_f32_16x16x32_bf16(A2[mt], B2, corr[mt][nt], 0, 0, 0);
            }
        }
    }

    float* outp = part + (size_t)blockIdx.y*BL*DD;
    #pragma unroll
    for (int mt = 0; mt < 2; ++mt)
        #pragma unroll
        for (int nt = 0; nt < 2; ++nt)
            #pragma unroll
            for (int reg = 0; reg < 4; ++reg) {
                const int row = row0 + mt*16 + quad*4 + reg;
                const int j   = wave*32 + nt*16 + m;
                outp[(size_t)row*DD + j] = accm[mt][nt][reg] + corr[mt][nt][reg];
            }
}

// ---------------------------------------------------------------------------
// Kernel 7: reduce the 4 K-split partials + bias.
// ---------------------------------------------------------------------------
__global__ __launch_bounds__(256) void proj_reduce_k(
    const float* __restrict__ part, const float* __restrict__ pb,
    float* __restrict__ out)
{
    const int gid = blockIdx.x*256 + threadIdx.x;
    if (gid >= BL*DD/4) return;
    const float4* p4 = (const float4*)part;
    float4 s = p4[gid];
    #pragma unroll
    for (int c = 1; c < 4; ++c) {
        float4 t = p4[gid + (size_t)c*(BL*DD/4)];
        s.x += t.x; s.y += t.y; s.z += t.z; s.w += t.w;
    }
    const int col = (gid << 2) & (DD-1);
    s.x += pb[col]; s.y += pb[col+1]; s.z += pb[col+2]; s.w += pb[col+3];
    ((float4*)out)[gid] = s;
}

// ---------------------------------------------------------------------------
extern "C" void kernel_launch(void* const* d_in, const int* in_sizes, int n_in,
                              void* d_out, int out_size, void* d_ws, size_t ws_size,
                              hipStream_t stream) {
    const float* x       = (const float*)d_in[0];
    const float* q_w     = (const float*)d_in[1];
    const float* q_b     = (const float*)d_in[2];
    const float* k_w     = (const float*)d_in[3];
    const float* k_b     = (const float*)d_in[4];
    const float* v_w     = (const float*)d_in[5];
    const float* g1_q    = (const float*)d_in[6];
    const float* g2_q    = (const float*)d_in[7];
    const float* g1_k    = (const float*)d_in[8];
    const float* g2_k    = (const float*)d_in[9];
    const float* gamma_q = (const float*)d_in[10];
    const float* beta_q  = (const float*)d_in[11];
    const float* gamma_k = (const float*)d_in[12];
    const float* beta_k  = (const float*)d_in[13];
    const float* proj_w  = (const float*)d_in[14];
    const float* proj_b  = (const float*)d_in[15];

    float* f = (float*)d_ws;
    float* q_s     = f;                        // 4,194,304 floats
    float* k_s     = f + 4194304;              // 4,194,304
    float* v_s     = f + 8388608;              // 4,194,304
    float* part_kv = f + 12582912;             // 4,194,304 (scratch: wenc/xenc/kv parts/proj parts)
    double* part_ks = (double*)(f + 16777216); // 32,768 doubles
    __bf16* kvt_enc = (__bf16*)(f + 16842752); // 524,288 bf16
    __bf16* genc   = (__bf16*)(f + 17104896);  // 196,608 bf16
    __bf16* venc   = (__bf16*)(f + 17203200);  // 262,144 bf16
    __bf16* penc   = (__bf16*)(f + 17334272);  // 262,144 bf16
    float* o_s     = k_s;                      // reuse (phi_k dead after kv_mfma)
    float* proj_part = part_kv;                // reuse (kv parts dead after kvreduce)
    __bf16* wenc   = (__bf16*)(f + 12582912);
    __bf16* xenc   = (__bf16*)(f + 13762560);

    dim3 blk(256);
    enc_fused_k<<<2816, blk, 0, stream>>>(q_w, k_w, v_w, proj_w,
                                          g1_q, g2_q, g1_k, g2_k, x,
                                          wenc, genc, venc, penc, xenc);
    conv_mfma_k<<<dim3(64,12), blk, 0, stream>>>(xenc, wenc, venc, q_b, k_b,
                                                 gamma_q, beta_q, gamma_k, beta_k,
                                                 q_s, k_s, v_s);
    sketch_mfma_k<<<2048, blk, 0, stream>>>(q_s, k_s, genc);
    kv_mfma_k<<<dim3(16,16), dim3(512), 0, stream>>>(k_s, v_s, part_kv, part_ks);
    kvreduce_k<<<1024, blk, 0, stream>>>(part_kv, kvt_enc);
    numden_mfma_k<<<dim3(32,16), blk, 0, stream>>>(q_s, kvt_enc, part_ks, o_s);
    proj_part_mfma_k<<<dim3(128,4), blk, 0, stream>>>(o_s, penc, proj_part);
    proj_reduce_k<<<512, blk, 0, stream>>>(proj_part, proj_b, (float*)d_out);
}

// Round 16
// 266.880 us; speedup vs baseline: 1.6219x; 1.6219x over previous
//
#include <hip/hip_runtime.h>
#include <math.h>

// Problem constants
#define BB 2
#define DD 128
#define LL 2048
#define HH 8
#define OC 1024     // H*D
#define RR_ 128
#define BL (BB*LL)          // 4096
#define NROW (BL*HH)        // 32768
#define XROWS 2052

// Numerics ledger (absmax bf16-quantized; threshold 180.48):
//   r3 full fp64 -> 128 PASS | r2 seq fp32 (~7e-7) -> 192 FAIL
//   r5 chunk32+tanhf (~5e-7) -> 192 FAIL | r6 chunk4/8+fp64 tanh -> 128 PASS
//   r7-r11 MFMA ladder -> 64 PASS | r12/r13 fast tanh -> FAIL (mistyped C)
//   r14 fixed C -> 64 PASS, 268us | r15 conv 4x o-tile batch -> 433us REGRESS:
//   VGPR 112->256, FETCH 23.6->322MB = accumulator SPILL (compiler pipelines
//   across serial o-tile loop). LESSON: don't batch GEMM tiles behind a
//   serial loop with live accumulator arrays at >100 VGPR.
// r16: exact revert of conv to r14 (grid.y=48, one o-tile per block).

typedef __bf16  bf16x8  __attribute__((ext_vector_type(8)));
typedef float   float4v __attribute__((ext_vector_type(4)));

__device__ __forceinline__ void enc2(const float* src, bf16x8& p1, bf16x8& p2) {
    #pragma unroll
    for (int j = 0; j < 8; ++j) {
        float v = src[j];
        __bf16 h1 = (__bf16)v;
        p1[j] = h1;
        p2[j] = (__bf16)(v - (float)h1);
    }
}

// phi = SR*tanh(u1*u2/SR) = SR*(1 - 2/(2^y + 1)), y = u1*u2*(2/sqrt(128))*log2e.
__device__ __forceinline__ float fast_phi(double u1, double u2) {
    const double TWO_ISR = 0.17677669529663688110;  // 2/sqrt(128) = sqrt(2)/8
    const double LOG2E   = 1.44269504088896340736;  // log2(e)
    const double SR      = 11.313708498984760390;   // sqrt(128)
    double y = (u1*u2) * (TWO_ISR * LOG2E);
    y = fmin(fmax(y, -1020.4), 1020.4);
    double n = rint(y);
    double f = y - n;
    float ff = (float)f;
    float q;
    q = fmaf(1.01780860092396960e-7f, ff, 1.32154867901443094e-6f);
    q = fmaf(q, ff, 1.52527338040598403e-5f);
    q = fmaf(q, ff, 1.54035303933816099e-4f);
    q = fmaf(q, ff, 1.33335581464284434e-3f);
    q = fmaf(q, ff, 9.61812910762847716e-3f);
    q = fmaf(q, ff, 5.55041086648215800e-2f);
    double t2   = fma(f, (double)q, 0.24022650695910071233);
    double head = fma(f, 0.69314718055994530942, 1.0);
    double E0   = fma(f*f, t2, head);
    int ni = (int)n;
    double En = __hiloint2double((ni + 1023) << 20, 0);   // 2^n
    double E  = E0 * En;
    double den = E + 1.0;
    double r = (double)__builtin_amdgcn_rcpf((float)den);
    r = r * fma(-den, r, 2.0);
    r = r * fma(-den, r, 2.0);
    double t = fma(-2.0, r, 1.0);
    return (float)(SR * t);
}

// ---------------------------------------------------------------------------
// Kernel 0: fused encode (weights + x). (r11-proven)
// ---------------------------------------------------------------------------
__global__ __launch_bounds__(256) void enc_fused_k(
    const float* __restrict__ q_w, const float* __restrict__ k_w,
    const float* __restrict__ v_w, const float* __restrict__ pw,
    const float* __restrict__ g1_q, const float* __restrict__ g2_q,
    const float* __restrict__ g1_k, const float* __restrict__ g2_k,
    const float* __restrict__ x,
    __bf16* __restrict__ wenc, __bf16* __restrict__ genc,
    __bf16* __restrict__ venc, __bf16* __restrict__ penc,
    __bf16* __restrict__ xenc)
{
    __shared__ float t[32][33];
    const int bid = blockIdx.x;
    const int tid = threadIdx.x;
    if (bid < 2304) {
        const int gid = bid*256 + tid;
        if (gid < 262144) {
            const int o = gid >> 7, c = gid & 127;
            #pragma unroll
            for (int tt = 0; tt < 3; ++tt) {
                float v = (o < 1024) ? q_w[(o*128 + c)*3 + tt]
                                     : k_w[((o-1024)*128 + c)*3 + tt];
                __bf16 h1 = (__bf16)v;  float r1 = v - (float)h1;
                __bf16 h2 = (__bf16)r1; float r2 = r1 - (float)h2;
                __bf16 h3 = (__bf16)r2;
                wenc[((size_t)(0*3 + tt)*2048 + o)*128 + c] = h1;
                wenc[((size_t)(1*3 + tt)*2048 + o)*128 + c] = h2;
                wenc[((size_t)(2*3 + tt)*2048 + o)*128 + c] = h3;
            }
        } else if (gid < 262144 + 65536) {
            const int g = gid - 262144;
            const int mat = g >> 14, rem = g & 16383;
            const int r = rem >> 7, d = rem & 127;
            const float* src = (mat == 0) ? g1_q : (mat == 1) ? g2_q
                             : (mat == 2) ? g1_k : g2_k;
            float v = src[d*RR_ + r];
            __bf16 h1 = (__bf16)v;  float r1 = v - (float)h1;
            __bf16 h2 = (__bf16)r1; float r2 = r1 - (float)h2;
            __bf16 h3 = (__bf16)r2;
            genc[((size_t)(mat*3 + 0)*128 + r)*128 + d] = h1;
            genc[((size_t)(mat*3 + 1)*128 + r)*128 + d] = h2;
            genc[((size_t)(mat*3 + 2)*128 + r)*128 + d] = h3;
        } else if (gid < 262144 + 65536 + 131072) {
            const int g = gid - 262144 - 65536;
            const int o = g >> 7, c = g & 127;
            float v = v_w[o*128 + c];
            __bf16 h1 = (__bf16)v;  float r1 = v - (float)h1;
            __bf16 h2 = (__bf16)r1;
            venc[((size_t)0*1024 + o)*128 + c] = h1;
            venc[((size_t)1*1024 + o)*128 + c] = h2;
        } else if (gid < 262144 + 65536 + 131072 + 131072) {
            const int g = gid - 262144 - 65536 - 131072;
            const int j = g >> 10, k = g & 1023;
            float v = pw[(size_t)j*OC + k];
            __bf16 h1 = (__bf16)v;  float r1 = v - (float)h1;
            __bf16 h2 = (__bf16)r1;
            penc[((size_t)(0*128 + j))*OC + k] = h1;
            penc[((size_t)(1*128 + j))*OC + k] = h2;
        }
    } else {
        const int g = bid - 2304;
        const int lt = g & 63, ct = (g >> 6) & 3, b = g >> 8;
        const int l0 = lt*32, c0 = ct*32;
        for (int e = tid; e < 32*32; e += 256) {
            int c = e >> 5, l = e & 31;
            t[c][l] = x[((size_t)(b*DD + c0 + c))*LL + l0 + l];
        }
        __syncthreads();
        for (int e = tid; e < 32*32; e += 256) {
            int l = e >> 5, c = e & 31;
            float v = t[c][l];
            __bf16 h1 = (__bf16)v;  float r1 = v - (float)h1;
            __bf16 h2 = (__bf16)r1; float r2 = r1 - (float)h2;
            __bf16 h3 = (__bf16)r2;
            const size_t row = (size_t)(l0 + l + 2);
            xenc[((size_t)(0*2 + b)*XROWS + row)*128 + c0 + c] = h1;
            xenc[((size_t)(1*2 + b)*XROWS + row)*128 + c0 + c] = h2;
            xenc[((size_t)(2*2 + b)*XROWS + row)*128 + c0 + c] = h3;
        }
        if (lt == 0 && ct == 0) {
            for (int e = tid; e < 2*128; e += 256) {
                int row = e >> 7, c = e & 127;
                xenc[((size_t)(0*2 + b)*XROWS + row)*128 + c] = (__bf16)0.f;
                xenc[((size_t)(1*2 + b)*XROWS + row)*128 + c] = (__bf16)0.f;
                xenc[((size_t)(2*2 + b)*XROWS + row)*128 + c] = (__bf16)0.f;
            }
        }
    }
}

// ---------------------------------------------------------------------------
// Kernel 1: fused q+k conv (3-plane/6-pass) AND v (2-plane/4-pass). (r14)
// grid (64, 48): y<32 -> q|k conv o-tile, y>=32 -> v o-tile.
// ---------------------------------------------------------------------------
__global__ __launch_bounds__(256) void conv_mfma_k(
    const __bf16* __restrict__ xenc, const __bf16* __restrict__ wenc,
    const __bf16* __restrict__ venc,
    const float* __restrict__ q_b, const float* __restrict__ k_b,
    const float* __restrict__ gamma_q, const float* __restrict__ beta_q,
    const float* __restrict__ gamma_k, const float* __restrict__ beta_k,
    float* __restrict__ q_s, float* __restrict__ k_s, float* __restrict__ v_s)
{
    __shared__ __bf16 As[3][66][136];
    const int tid  = threadIdx.x;
    const int wave = tid >> 6;
    const int lane = tid & 63;
    const int m    = lane & 15;
    const int quad = lane >> 4;
    const int bx = blockIdx.x;
    const int b  = bx >> 5;
    const int lb0 = (bx & 31) << 6;
    const int yt = blockIdx.y;

    for (int e = tid; e < 3*66*16; e += 256) {
        const int p = e / (66*16), rem = e % (66*16);
        const int row = rem >> 4, cg = rem & 15;
        *(bf16x8*)&As[p][row][cg*8] =
            *(const bf16x8*)&xenc[((size_t)(p*2 + b)*XROWS + lb0 + row)*128 + cg*8];
    }
    __syncthreads();

    if (yt < 32) {
        const int o0 = yt << 6;
        const int osub = o0 + wave*16;
        float4v accm[4][4];
        float4v corr[4][2];
        #pragma unroll
        for (int lt = 0; lt < 4; ++lt) {
            corr[lt][0] = (float4v){0.f,0.f,0.f,0.f};
            corr[lt][1] = (float4v){0.f,0.f,0.f,0.f};
            #pragma unroll
            for (int c = 0; c < 4; ++c) accm[lt][c] = (float4v){0.f,0.f,0.f,0.f};
        }
        #pragma unroll
        for (int cidx = 0; cidx < 4; ++cidx) {
            const int c0 = cidx << 5;
            #pragma unroll
            for (int t = 0; t < 3; ++t) {
                bf16x8 B1, B2, B3;
                {
                    size_t base = ((size_t)t*2048 + osub + m)*128 + c0 + quad*8;
                    B1 = *(const bf16x8*)&wenc[base];
                    B2 = *(const bf16x8*)&wenc[base + (size_t)3*2048*128];
                    B3 = *(const bf16x8*)&wenc[base + (size_t)6*2048*128];
                }
                #pragma unroll
                for (int lt = 0; lt < 4; ++lt) {
                    const int row = lt*16 + m + t;
                    bf16x8 A1 = *(const bf16x8*)&As[0][row][c0 + quad*8];
                    bf16x8 A2 = *(const bf16x8*)&As[1][row][c0 + quad*8];
                    bf16x8 A3 = *(const bf16x8*)&As[2][row][c0 + quad*8];
                    accm[lt][cidx] = __builtin_amdgcn_mfma_f32_16x16x32_bf16(A1, B1, accm[lt][cidx], 0, 0, 0);
                    corr[lt][0] = __builtin_amdgcn_mfma_f32_16x16x32_bf16(A1, B2, corr[lt][0], 0, 0, 0);
                    corr[lt][1] = __builtin_amdgcn_mfma_f32_16x16x32_bf16(A2, B1, corr[lt][1], 0, 0, 0);
                    corr[lt][0] = __builtin_amdgcn_mfma_f32_16x16x32_bf16(A1, B3, corr[lt][0], 0, 0, 0);
                    corr[lt][1] = __builtin_amdgcn_mfma_f32_16x16x32_bf16(A3, B1, corr[lt][1], 0, 0, 0);
                    corr[lt][0] = __builtin_amdgcn_mfma_f32_16x16x32_bf16(A2, B2, corr[lt][0], 0, 0, 0);
                }
            }
        }
        const int is_k = (o0 >= 1024);
        const double g  = (double)(is_k ? gamma_k[0] : gamma_q[0]);
        const double be = (double)(is_k ? beta_k[0]  : beta_q[0]);
        const int o_global = osub + m;
        const int o_local  = o_global - (is_k ? 1024 : 0);
        const double bias  = (double)(is_k ? k_b[o_local] : q_b[o_local]);
        float* dest = is_k ? k_s : q_s;
        #pragma unroll
        for (int lt = 0; lt < 4; ++lt) {
            #pragma unroll
            for (int reg = 0; reg < 4; ++reg) {
                double s = (double)corr[lt][0][reg] + (double)corr[lt][1][reg];
                #pragma unroll
                for (int c = 0; c < 4; ++c) s += (double)accm[lt][c][reg];
                const int l = lb0 + lt*16 + quad*4 + reg;
                dest[((size_t)(b*LL + l))*OC + o_local] = (float)(g*(s + bias) + be);
            }
        }
    } else {
        const int o0 = (yt - 32) << 6;
        const int osub = o0 + wave*16;
        float4v accm[4][4];
        float4v corr[4];
        #pragma unroll
        for (int lt = 0; lt < 4; ++lt) {
            corr[lt] = (float4v){0.f,0.f,0.f,0.f};
            #pragma unroll
            for (int c = 0; c < 4; ++c) accm[lt][c] = (float4v){0.f,0.f,0.f,0.f};
        }
        #pragma unroll
        for (int cidx = 0; cidx < 4; ++cidx) {
            const int c0 = cidx << 5;
            bf16x8 B1, B2;
            {
                size_t base = ((size_t)(osub + m))*128 + c0 + quad*8;
                B1 = *(const bf16x8*)&venc[base];
                B2 = *(const bf16x8*)&venc[base + (size_t)1024*128];
            }
            #pragma unroll
            for (int lt = 0; lt < 4; ++lt) {
                const int row = lt*16 + m + 2;
                bf16x8 A1 = *(const bf16x8*)&As[0][row][c0 + quad*8];
                bf16x8 A2 = *(const bf16x8*)&As[1][row][c0 + quad*8];
                accm[lt][cidx] = __builtin_amdgcn_mfma_f32_16x16x32_bf16(A1, B1, accm[lt][cidx], 0, 0, 0);
                corr[lt] = __builtin_amdgcn_mfma_f32_16x16x32_bf16(A1, B2, corr[lt], 0, 0, 0);
                corr[lt] = __builtin_amdgcn_mfma_f32_16x16x32_bf16(A2, B1, corr[lt], 0, 0, 0);
                corr[lt] = __builtin_amdgcn_mfma_f32_16x16x32_bf16(A2, B2, corr[lt], 0, 0, 0);
            }
        }
        const int o_local = osub + m;
        #pragma unroll
        for (int lt = 0; lt < 4; ++lt) {
            #pragma unroll
            for (int reg = 0; reg < 4; ++reg) {
                float s = corr[lt][reg];
                #pragma unroll
                for (int c = 0; c < 4; ++c) s += accm[lt][c][reg];
                const int l = lb0 + lt*16 + quad*4 + reg;
                v_s[((size_t)(b*LL + l))*OC + o_local] = s;
            }
        }
    }
}

// ---------------------------------------------------------------------------
// Kernel 2: sketch q+k fused, 3-plane/6-pass MFMA in-place; fast_phi epilogue.
// ---------------------------------------------------------------------------
__global__ __launch_bounds__(256) void sketch_mfma_k(
    float* __restrict__ q_s, float* __restrict__ k_s,
    const __bf16* __restrict__ genc_all)
{
    __shared__ __bf16 As[3][32][136];
    const int tid  = threadIdx.x;
    const int wave = tid >> 6;
    const int lane = tid & 63;
    const int m    = lane & 15;
    const int quad = lane >> 4;
    const int half = blockIdx.x >> 10;
    float* buf = half ? k_s : q_s;
    const __bf16* genc = genc_all + (size_t)half*2*3*128*128;
    const size_t i0 = (size_t)(blockIdx.x & 1023) * 32;

    for (int e = tid; e < 32*128; e += 256) {
        int row = e >> 7, d = e & 127;
        float v = buf[(i0 + row)*RR_ + d];
        __bf16 h1 = (__bf16)v;  float r1 = v - (float)h1;
        __bf16 h2 = (__bf16)r1; float r2 = r1 - (float)h2;
        __bf16 h3 = (__bf16)r2;
        As[0][row][d] = h1; As[1][row][d] = h2; As[2][row][d] = h3;
    }
    __syncthreads();

    float4v accm[2][2][2], corr[2][2][2];
    #pragma unroll
    for (int mt = 0; mt < 2; ++mt)
        #pragma unroll
        for (int nt = 0; nt < 2; ++nt)
            #pragma unroll
            for (int mat = 0; mat < 2; ++mat) {
                accm[mt][nt][mat] = (float4v){0.f,0.f,0.f,0.f};
                corr[mt][nt][mat] = (float4v){0.f,0.f,0.f,0.f};
            }

    #pragma unroll
    for (int ck = 0; ck < 4; ++ck) {
        const int k0 = ck << 5;
        bf16x8 A1[2], A2[2], A3[2];
        #pragma unroll
        for (int mt = 0; mt < 2; ++mt) {
            A1[mt] = *(const bf16x8*)&As[0][mt*16 + m][k0 + quad*8];
            A2[mt] = *(const bf16x8*)&As[1][mt*16 + m][k0 + quad*8];
            A3[mt] = *(const bf16x8*)&As[2][mt*16 + m][k0 + quad*8];
        }
        #pragma unroll
        for (int nt = 0; nt < 2; ++nt) {
            const int r = wave*32 + nt*16 + m;
            #pragma unroll
            for (int mat = 0; mat < 2; ++mat) {
                size_t base = ((size_t)(mat*3)*128 + r)*128 + k0 + quad*8;
                bf16x8 B1 = *(const bf16x8*)&genc[base];
                bf16x8 B2 = *(const bf16x8*)&genc[base + (size_t)128*128];
                bf16x8 B3 = *(const bf16x8*)&genc[base + (size_t)2*128*128];
                #pragma unroll
                for (int mt = 0; mt < 2; ++mt) {
                    accm[mt][nt][mat] = __builtin_amdgcn_mfma_f32_16x16x32_bf16(A1[mt], B1, accm[mt][nt][mat], 0, 0, 0);
                    corr[mt][nt][mat] = __builtin_amdgcn_mfma_f32_16x16x32_bf16(A1[mt], B2, corr[mt][nt][mat], 0, 0, 0);
                    corr[mt][nt][mat] = __builtin_amdgcn_mfma_f32_16x16x32_bf16(A2[mt], B1, corr[mt][nt][mat], 0, 0, 0);
                    corr[mt][nt][mat] = __builtin_amdgcn_mfma_f32_16x16x32_bf16(A1[mt], B3, corr[mt][nt][mat], 0, 0, 0);
                    corr[mt][nt][mat] = __builtin_amdgcn_mfma_f32_16x16x32_bf16(A3[mt], B1, corr[mt][nt][mat], 0, 0, 0);
                    corr[mt][nt][mat] = __builtin_amdgcn_mfma_f32_16x16x32_bf16(A2[mt], B2, corr[mt][nt][mat], 0, 0, 0);
                }
            }
        }
    }
    __syncthreads();

    #pragma unroll
    for (int mt = 0; mt < 2; ++mt)
        #pragma unroll
        for (int nt = 0; nt < 2; ++nt)
            #pragma unroll
            for (int reg = 0; reg < 4; ++reg) {
                double u1 = (double)accm[mt][nt][0][reg] + (double)corr[mt][nt][0][reg];
                double u2 = (double)accm[mt][nt][1][reg] + (double)corr[mt][nt][1][reg];
                const size_t row = i0 + mt*16 + quad*4 + reg;
                const int col = wave*32 + nt*16 + m;
                buf[row*RR_ + col] = fast_phi(u1, u2);
            }
}

// ---------------------------------------------------------------------------
// Kernel 3: KV^T partials via 2-plane MFMA + fp64 Ksum partials (r10-proven).
// ---------------------------------------------------------------------------
__global__ __launch_bounds__(512) void kv_mfma_k(
    const float* __restrict__ phi_k, const float* __restrict__ v,
    float* __restrict__ part_kv, double* __restrict__ part_ks)
{
    __shared__ float Pt[128*36];
    __shared__ float Vt[128*36];
    __shared__ double ksred[512];
    const int tid  = threadIdx.x;
    const int wave = tid >> 6;
    const int lane = tid & 63;
    const int m    = lane & 15;
    const int quad = lane >> 4;
    const int split = blockIdx.x;
    const int bh    = blockIdx.y;
    const int b = bh >> 3, h = bh & 7;
    const int lbase = split * 128;
    const int dh = wave & 1;
    const int rq = wave >> 1;

    float4v accm[4][2], corr[4][2];
    #pragma unroll
    for (int mt = 0; mt < 4; ++mt)
        #pragma unroll
        for (int nt = 0; nt < 2; ++nt) {
            accm[mt][nt] = (float4v){0.f,0.f,0.f,0.f};
            corr[mt][nt] = (float4v){0.f,0.f,0.f,0.f};
        }
    double ks = 0.0;

    for (int ch = 0; ch < 4; ++ch) {
        __syncthreads();
        for (int e = tid; e < 32*128; e += 512) {
            const int l = e >> 7, r = e & 127;
            size_t base = ((size_t)(b*LL + lbase + ch*32 + l)*HH + h)*RR_;
            float pv = phi_k[base + r];
            float vv = v[base + r];
            Pt[r*36 + l] = pv;
            Vt[r*36 + l] = vv;
            ks += (double)pv;
        }
        __syncthreads();
        bf16x8 A1[4], A2[4], B1[2], B2[2];
        #pragma unroll
        for (int mt = 0; mt < 4; ++mt)
            enc2(&Vt[(dh*64 + mt*16 + m)*36 + quad*8], A1[mt], A2[mt]);
        #pragma unroll
        for (int nt = 0; nt < 2; ++nt)
            enc2(&Pt[(rq*32 + nt*16 + m)*36 + quad*8], B1[nt], B2[nt]);
        #pragma unroll
        for (int mt = 0; mt < 4; ++mt)
            #pragma unroll
            for (int nt = 0; nt < 2; ++nt) {
                accm[mt][nt] = __builtin_amdgcn_mfma_f32_16x16x32_bf16(A1[mt], B1[nt], accm[mt][nt], 0, 0, 0);
                corr[mt][nt] = __builtin_amdgcn_mfma_f32_16x16x32_bf16(A1[mt], B2[nt], corr[mt][nt], 0, 0, 0);
                corr[mt][nt] = __builtin_amdgcn_mfma_f32_16x16x32_bf16(A2[mt], B1[nt], corr[mt][nt], 0, 0, 0);
                corr[mt][nt] = __builtin_amdgcn_mfma_f32_16x16x32_bf16(A2[mt], B2[nt], corr[mt][nt], 0, 0, 0);
            }
    }

    ksred[tid] = ks;
    __syncthreads();
    if (tid < 128) {
        double s = ksred[tid] + ksred[tid+128] + ksred[tid+256] + ksred[tid+384];
        part_ks[(bh*16 + split)*RR_ + tid] = s;
    }

    float* outp = part_kv + ((size_t)(bh*16 + split))*RR_*DD;
    #pragma unroll
    for (int mt = 0; mt < 4; ++mt)
        #pragma unroll
        for (int nt = 0; nt < 2; ++nt)
            #pragma unroll
            for (int reg = 0; reg < 4; ++reg) {
                const int d = dh*64 + mt*16 + quad*4 + reg;
                const int r = rq*32 + nt*16 + m;
                outp[d*128 + r] = accm[mt][nt][reg] + corr[mt][nt][reg];
            }
}

// ---------------------------------------------------------------------------
// Kernel 4: reduce KVT partials -> bf16 2-plane KVTenc.
// ---------------------------------------------------------------------------
__global__ __launch_bounds__(256) void kvreduce_k(
    const float* __restrict__ part_kv, __bf16* __restrict__ kvt_enc)
{
    const int gid = blockIdx.x*256 + threadIdx.x;
    if (gid >= 16*RR_*DD) return;
    const int bh = gid >> 14;
    const int rd = gid & 16383;
    float s = 0.f;
    #pragma unroll
    for (int c = 0; c < 16; ++c)
        s += part_kv[(((size_t)(bh*16 + c)) << 14) + rd];
    __bf16 h1 = (__bf16)s;
    __bf16 h2 = (__bf16)(s - (float)h1);
    kvt_enc[(size_t)bh*16384 + rd] = h1;
    kvt_enc[(size_t)(16 + bh)*16384 + rd] = h2;
}

// ---------------------------------------------------------------------------
// Kernel 5: numerator MFMA + fp64 den (r10-proven).
// ---------------------------------------------------------------------------
__global__ __launch_bounds__(256) void numden_mfma_k(
    const float* __restrict__ phi_q, const __bf16* __restrict__ kvt_enc,
    const double* __restrict__ part_ks, float* __restrict__ o_out)
{
    __shared__ float Pq[64*132];
    __shared__ double Ks_s[128];
    __shared__ double den_s[64];
    const int tid  = threadIdx.x;
    const int wave = tid >> 6;
    const int lane = tid & 63;
    const int m    = lane & 15;
    const int quad = lane >> 4;
    const int lt = blockIdx.x;
    const int bh = blockIdx.y;
    const int b = bh >> 3, h = bh & 7;
    const int l0 = lt * 64;

    if (tid < 128) {
        double s = 0.0;
        #pragma unroll
        for (int c = 0; c < 16; ++c) s += part_ks[(bh*16 + c)*RR_ + tid];
        Ks_s[tid] = s;
    }
    for (int e = tid; e < 64*128; e += 256) {
        const int l = e >> 7, r = e & 127;
        Pq[l*132 + r] = phi_q[((size_t)(b*LL + l0 + l)*HH + h)*RR_ + r];
    }
    __syncthreads();

    double den = 0.0;
    if (tid < 64) {
        #pragma unroll
        for (int r = 0; r < 128; ++r)
            den += (double)Pq[tid*132 + r] * Ks_s[r];
    }

    float4v accm[4][2], corr[4][2];
    #pragma unroll
    for (int mt = 0; mt < 4; ++mt)
        #pragma unroll
        for (int nt = 0; nt < 2; ++nt) {
            accm[mt][nt] = (float4v){0.f,0.f,0.f,0.f};
            corr[mt][nt] = (float4v){0.f,0.f,0.f,0.f};
        }

    #pragma unroll
    for (int ck = 0; ck < 4; ++ck) {
        const int k0 = ck << 5;
        bf16x8 A1[4], A2[4];
        #pragma unroll
        for (int mt = 0; mt < 4; ++mt)
            enc2(&Pq[(mt*16 + m)*132 + k0 + quad*8], A1[mt], A2[mt]);
        #pragma unroll
        for (int nt = 0; nt < 2; ++nt) {
            const int d = wave*32 + nt*16 + m;
            size_t base = ((size_t)bh*128 + d)*128 + k0 + quad*8;
            bf16x8 B1 = *(const bf16x8*)&kvt_enc[base];
            bf16x8 B2 = *(const bf16x8*)&kvt_enc[base + (size_t)16*16384];
            #pragma unroll
            for (int mt = 0; mt < 4; ++mt) {
                accm[mt][nt] = __builtin_amdgcn_mfma_f32_16x16x32_bf16(A1[mt], B1, accm[mt][nt], 0, 0, 0);
                corr[mt][nt] = __builtin_amdgcn_mfma_f32_16x16x32_bf16(A1[mt], B2, corr[mt][nt], 0, 0, 0);
                corr[mt][nt] = __builtin_amdgcn_mfma_f32_16x16x32_bf16(A2[mt], B1, corr[mt][nt], 0, 0, 0);
                corr[mt][nt] = __builtin_amdgcn_mfma_f32_16x16x32_bf16(A2[mt], B2, corr[mt][nt], 0, 0, 0);
            }
        }
    }

    __syncthreads();
    if (tid < 64) den_s[tid] = den;
    __syncthreads();

    #pragma unroll
    for (int mt = 0; mt < 4; ++mt)
        #pragma unroll
        for (int nt = 0; nt < 2; ++nt)
            #pragma unroll
            for (int reg = 0; reg < 4; ++reg) {
                const int ll = mt*16 + quad*4 + reg;
                const int d  = wave*32 + nt*16 + m;
                const float inv = (float)(1.0 / (den_s[ll] + 1e-6));
                o_out[((size_t)(b*LL + l0 + ll))*OC + h*DD + d] =
                    (accm[mt][nt][reg] + corr[mt][nt][reg]) * inv;
            }
}

// ---------------------------------------------------------------------------
// Kernel 6: output projection partials via 2-plane MFMA (r10-proven).
// ---------------------------------------------------------------------------
__global__ __launch_bounds__(256) void proj_part_mfma_k(
    const float* __restrict__ o_s, const __bf16* __restrict__ penc,
    float* __restrict__ part)
{
    __shared__ float As[32*260];
    const int tid  = threadIdx.x;
    const int wave = tid >> 6;
    const int lane = tid & 63;
    const int m    = lane & 15;
    const int quad = lane >> 4;
    const int row0  = blockIdx.x * 32;
    const int kbase = blockIdx.y * 256;

    for (int e = tid; e < 32*256; e += 256) {
        const int row = e >> 8, k = e & 255;
        As[row*260 + k] = o_s[(size_t)(row0 + row)*OC + kbase + k];
    }
    __syncthreads();

    float4v accm[2][2], corr[2][2];
    #pragma unroll
    for (int mt = 0; mt < 2; ++mt)
        #pragma unroll
        for (int nt = 0; nt < 2; ++nt) {
            accm[mt][nt] = (float4v){0.f,0.f,0.f,0.f};
            corr[mt][nt] = (float4v){0.f,0.f,0.f,0.f};
        }

    #pragma unroll
    for (int ck = 0; ck < 8; ++ck) {
        const int k0 = ck << 5;
        bf16x8 A1[2], A2[2];
        #pragma unroll
        for (int mt = 0; mt < 2; ++mt)
            enc2(&As[(mt*16 + m)*260 + k0 + quad*8], A1[mt], A2[mt]);
        #pragma unroll
        for (int nt = 0; nt < 2; ++nt) {
            const int j = wave*32 + nt*16 + m;
            size_t base = ((size_t)j)*OC + kbase + k0 + quad*8;
            bf16x8 B1 = *(const bf16x8*)&penc[base];
            bf16x8 B2 = *(const bf16x8*)&penc[base + (size_t)128*OC];
            #pragma unroll
            for (int mt = 0; mt < 2; ++mt) {
                accm[mt][nt] = __builtin_amdgcn_mfma_f32_16x16x32_bf16(A1[mt], B1, accm[mt][nt], 0, 0, 0);
                corr[mt][nt] = __builtin_amdgcn_mfma_f32_16x16x32_bf16(A1[mt], B2, corr[mt][nt], 0, 0, 0);
                corr[mt][nt] = __builtin_amdgcn_mfma_f32_16x16x32_bf16(A2[mt], B1, corr[mt][nt], 0, 0, 0);
                corr[mt][nt] = __builtin_amdgcn_mfma_f32_16x16x32_bf16(A2[mt], B2, corr[mt][nt], 0, 0, 0);
            }
        }
    }

    float* outp = part + (size_t)blockIdx.y*BL*DD;
    #pragma unroll
    for (int mt = 0; mt < 2; ++mt)
        #pragma unroll
        for (int nt = 0; nt < 2; ++nt)
            #pragma unroll
            for (int reg = 0; reg < 4; ++reg) {
                const int row = row0 + mt*16 + quad*4 + reg;
                const int j   = wave*32 + nt*16 + m;
                outp[(size_t)row*DD + j] = accm[mt][nt][reg] + corr[mt][nt][reg];
            }
}

// ---------------------------------------------------------------------------
// Kernel 7: reduce the 4 K-split partials + bias.
// ---------------------------------------------------------------------------
__global__ __launch_bounds__(256) void proj_reduce_k(
    const float* __restrict__ part, const float* __restrict__ pb,
    float* __restrict__ out)
{
    const int gid = blockIdx.x*256 + threadIdx.x;
    if (gid >= BL*DD/4) return;
    const float4* p4 = (const float4*)part;
    float4 s = p4[gid];
    #pragma unroll
    for (int c = 1; c < 4; ++c) {
        float4 t = p4[gid + (size_t)c*(BL*DD/4)];
        s.x += t.x; s.y += t.y; s.z += t.z; s.w += t.w;
    }
    const int col = (gid << 2) & (DD-1);
    s.x += pb[col]; s.y += pb[col+1]; s.z += pb[col+2]; s.w += pb[col+3];
    ((float4*)out)[gid] = s;
}

// ---------------------------------------------------------------------------
extern "C" void kernel_launch(void* const* d_in, const int* in_sizes, int n_in,
                              void* d_out, int out_size, void* d_ws, size_t ws_size,
                              hipStream_t stream) {
    const float* x       = (const float*)d_in[0];
    const float* q_w     = (const float*)d_in[1];
    const float* q_b     = (const float*)d_in[2];
    const float* k_w     = (const float*)d_in[3];
    const float* k_b     = (const float*)d_in[4];
    const float* v_w     = (const float*)d_in[5];
    const float* g1_q    = (const float*)d_in[6];
    const float* g2_q    = (const float*)d_in[7];
    const float* g1_k    = (const float*)d_in[8];
    const float* g2_k    = (const float*)d_in[9];
    const float* gamma_q = (const float*)d_in[10];
    const float* beta_q  = (const float*)d_in[11];
    const float* gamma_k = (const float*)d_in[12];
    const float* beta_k  = (const float*)d_in[13];
    const float* proj_w  = (const float*)d_in[14];
    const float* proj_b  = (const float*)d_in[15];

    float* f = (float*)d_ws;
    float* q_s     = f;                        // 4,194,304 floats
    float* k_s     = f + 4194304;              // 4,194,304
    float* v_s     = f + 8388608;              // 4,194,304
    float* part_kv = f + 12582912;             // 4,194,304 (scratch: wenc/xenc/kv parts/proj parts)
    double* part_ks = (double*)(f + 16777216); // 32,768 doubles
    __bf16* kvt_enc = (__bf16*)(f + 16842752); // 524,288 bf16
    __bf16* genc   = (__bf16*)(f + 17104896);  // 196,608 bf16
    __bf16* venc   = (__bf16*)(f + 17203200);  // 262,144 bf16
    __bf16* penc   = (__bf16*)(f + 17334272);  // 262,144 bf16
    float* o_s     = k_s;                      // reuse (phi_k dead after kv_mfma)
    float* proj_part = part_kv;                // reuse (kv parts dead after kvreduce)
    __bf16* wenc   = (__bf16*)(f + 12582912);
    __bf16* xenc   = (__bf16*)(f + 13762560);

    dim3 blk(256);
    enc_fused_k<<<2816, blk, 0, stream>>>(q_w, k_w, v_w, proj_w,
                                          g1_q, g2_q, g1_k, g2_k, x,
                                          wenc, genc, venc, penc, xenc);
    conv_mfma_k<<<dim3(64,48), blk, 0, stream>>>(xenc, wenc, venc, q_b, k_b,
                                                 gamma_q, beta_q, gamma_k, beta_k,
                                                 q_s, k_s, v_s);
    sketch_mfma_k<<<2048, blk, 0, stream>>>(q_s, k_s, genc);
    kv_mfma_k<<<dim3(16,16), dim3(512), 0, stream>>>(k_s, v_s, part_kv, part_ks);
    kvreduce_k<<<1024, blk, 0, stream>>>(part_kv, kvt_enc);
    numden_mfma_k<<<dim3(32,16), blk, 0, stream>>>(q_s, kvt_enc, part_ks, o_s);
    proj_part_mfma_k<<<dim3(128,4), blk, 0, stream>>>(o_s, penc, proj_part);
    proj_reduce_k<<<512, blk, 0, stream>>>(proj_part, proj_b, (float*)d_out);
}

// Round 17
// 264.513 us; speedup vs baseline: 1.6364x; 1.0090x over previous
//
#include <hip/hip_runtime.h>
#include <math.h>

// Problem constants
#define BB 2
#define DD 128
#define LL 2048
#define HH 8
#define OC 1024     // H*D
#define RR_ 128
#define BL (BB*LL)          // 4096
#define NROW (BL*HH)        // 32768
#define XROWS 2052

// Numerics ledger (absmax bf16-quantized; threshold 180.48):
//   r3 full fp64 -> 128 PASS | r2 seq fp32 (~7e-7) -> 192 FAIL
//   r5 chunk32+tanhf (~5e-7) -> 192 FAIL | r6 chunk4/8+fp64 tanh -> 128 PASS
//   r7-r11 MFMA ladder -> 64 PASS | r12/r13 fast tanh -> FAIL (mistyped C)
//   r14 fixed C -> 64 PASS, 268us | r15 conv 4x o-tile batch -> 433us REGRESS
//   (VGPR 256, accumulator spill). r16 revert -> 267us.
// r17: conv B-frag double-buffer prefetch (one round ahead). LDS caps conv
//      at 3 waves/SIMD; VGPR cap only binds >170, so +24 VGPR is free.
//      MFMA order per round unchanged -> bit-identical arithmetic.

typedef __bf16  bf16x8  __attribute__((ext_vector_type(8)));
typedef float   float4v __attribute__((ext_vector_type(4)));

__device__ __forceinline__ void enc2(const float* src, bf16x8& p1, bf16x8& p2) {
    #pragma unroll
    for (int j = 0; j < 8; ++j) {
        float v = src[j];
        __bf16 h1 = (__bf16)v;
        p1[j] = h1;
        p2[j] = (__bf16)(v - (float)h1);
    }
}

// phi = SR*tanh(u1*u2/SR) = SR*(1 - 2/(2^y + 1)), y = u1*u2*(2/sqrt(128))*log2e.
__device__ __forceinline__ float fast_phi(double u1, double u2) {
    const double TWO_ISR = 0.17677669529663688110;  // 2/sqrt(128) = sqrt(2)/8
    const double LOG2E   = 1.44269504088896340736;  // log2(e)
    const double SR      = 11.313708498984760390;   // sqrt(128)
    double y = (u1*u2) * (TWO_ISR * LOG2E);
    y = fmin(fmax(y, -1020.4), 1020.4);
    double n = rint(y);
    double f = y - n;
    float ff = (float)f;
    float q;
    q = fmaf(1.01780860092396960e-7f, ff, 1.32154867901443094e-6f);
    q = fmaf(q, ff, 1.52527338040598403e-5f);
    q = fmaf(q, ff, 1.54035303933816099e-4f);
    q = fmaf(q, ff, 1.33335581464284434e-3f);
    q = fmaf(q, ff, 9.61812910762847716e-3f);
    q = fmaf(q, ff, 5.55041086648215800e-2f);
    double t2   = fma(f, (double)q, 0.24022650695910071233);
    double head = fma(f, 0.69314718055994530942, 1.0);
    double E0   = fma(f*f, t2, head);
    int ni = (int)n;
    double En = __hiloint2double((ni + 1023) << 20, 0);   // 2^n
    double E  = E0 * En;
    double den = E + 1.0;
    double r = (double)__builtin_amdgcn_rcpf((float)den);
    r = r * fma(-den, r, 2.0);
    r = r * fma(-den, r, 2.0);
    double t = fma(-2.0, r, 1.0);
    return (float)(SR * t);
}

// ---------------------------------------------------------------------------
// Kernel 0: fused encode (weights + x). (r11-proven)
// ---------------------------------------------------------------------------
__global__ __launch_bounds__(256) void enc_fused_k(
    const float* __restrict__ q_w, const float* __restrict__ k_w,
    const float* __restrict__ v_w, const float* __restrict__ pw,
    const float* __restrict__ g1_q, const float* __restrict__ g2_q,
    const float* __restrict__ g1_k, const float* __restrict__ g2_k,
    const float* __restrict__ x,
    __bf16* __restrict__ wenc, __bf16* __restrict__ genc,
    __bf16* __restrict__ venc, __bf16* __restrict__ penc,
    __bf16* __restrict__ xenc)
{
    __shared__ float t[32][33];
    const int bid = blockIdx.x;
    const int tid = threadIdx.x;
    if (bid < 2304) {
        const int gid = bid*256 + tid;
        if (gid < 262144) {
            const int o = gid >> 7, c = gid & 127;
            #pragma unroll
            for (int tt = 0; tt < 3; ++tt) {
                float v = (o < 1024) ? q_w[(o*128 + c)*3 + tt]
                                     : k_w[((o-1024)*128 + c)*3 + tt];
                __bf16 h1 = (__bf16)v;  float r1 = v - (float)h1;
                __bf16 h2 = (__bf16)r1; float r2 = r1 - (float)h2;
                __bf16 h3 = (__bf16)r2;
                wenc[((size_t)(0*3 + tt)*2048 + o)*128 + c] = h1;
                wenc[((size_t)(1*3 + tt)*2048 + o)*128 + c] = h2;
                wenc[((size_t)(2*3 + tt)*2048 + o)*128 + c] = h3;
            }
        } else if (gid < 262144 + 65536) {
            const int g = gid - 262144;
            const int mat = g >> 14, rem = g & 16383;
            const int r = rem >> 7, d = rem & 127;
            const float* src = (mat == 0) ? g1_q : (mat == 1) ? g2_q
                             : (mat == 2) ? g1_k : g2_k;
            float v = src[d*RR_ + r];
            __bf16 h1 = (__bf16)v;  float r1 = v - (float)h1;
            __bf16 h2 = (__bf16)r1; float r2 = r1 - (float)h2;
            __bf16 h3 = (__bf16)r2;
            genc[((size_t)(mat*3 + 0)*128 + r)*128 + d] = h1;
            genc[((size_t)(mat*3 + 1)*128 + r)*128 + d] = h2;
            genc[((size_t)(mat*3 + 2)*128 + r)*128 + d] = h3;
        } else if (gid < 262144 + 65536 + 131072) {
            const int g = gid - 262144 - 65536;
            const int o = g >> 7, c = g & 127;
            float v = v_w[o*128 + c];
            __bf16 h1 = (__bf16)v;  float r1 = v - (float)h1;
            __bf16 h2 = (__bf16)r1;
            venc[((size_t)0*1024 + o)*128 + c] = h1;
            venc[((size_t)1*1024 + o)*128 + c] = h2;
        } else if (gid < 262144 + 65536 + 131072 + 131072) {
            const int g = gid - 262144 - 65536 - 131072;
            const int j = g >> 10, k = g & 1023;
            float v = pw[(size_t)j*OC + k];
            __bf16 h1 = (__bf16)v;  float r1 = v - (float)h1;
            __bf16 h2 = (__bf16)r1;
            penc[((size_t)(0*128 + j))*OC + k] = h1;
            penc[((size_t)(1*128 + j))*OC + k] = h2;
        }
    } else {
        const int g = bid - 2304;
        const int lt = g & 63, ct = (g >> 6) & 3, b = g >> 8;
        const int l0 = lt*32, c0 = ct*32;
        for (int e = tid; e < 32*32; e += 256) {
            int c = e >> 5, l = e & 31;
            t[c][l] = x[((size_t)(b*DD + c0 + c))*LL + l0 + l];
        }
        __syncthreads();
        for (int e = tid; e < 32*32; e += 256) {
            int l = e >> 5, c = e & 31;
            float v = t[c][l];
            __bf16 h1 = (__bf16)v;  float r1 = v - (float)h1;
            __bf16 h2 = (__bf16)r1; float r2 = r1 - (float)h2;
            __bf16 h3 = (__bf16)r2;
            const size_t row = (size_t)(l0 + l + 2);
            xenc[((size_t)(0*2 + b)*XROWS + row)*128 + c0 + c] = h1;
            xenc[((size_t)(1*2 + b)*XROWS + row)*128 + c0 + c] = h2;
            xenc[((size_t)(2*2 + b)*XROWS + row)*128 + c0 + c] = h3;
        }
        if (lt == 0 && ct == 0) {
            for (int e = tid; e < 2*128; e += 256) {
                int row = e >> 7, c = e & 127;
                xenc[((size_t)(0*2 + b)*XROWS + row)*128 + c] = (__bf16)0.f;
                xenc[((size_t)(1*2 + b)*XROWS + row)*128 + c] = (__bf16)0.f;
                xenc[((size_t)(2*2 + b)*XROWS + row)*128 + c] = (__bf16)0.f;
            }
        }
    }
}

// ---------------------------------------------------------------------------
// Kernel 1: fused q+k conv (3-plane/6-pass) AND v (2-plane/4-pass).
// r17: B-frag double-buffer — prefetch round i+1's wenc/venc frags while
// round i's MFMAs execute. MFMA sequence per round identical to r14.
// grid (64, 48): y<32 -> q|k conv o-tile, y>=32 -> v o-tile.
// ---------------------------------------------------------------------------
__global__ __launch_bounds__(256) void conv_mfma_k(
    const __bf16* __restrict__ xenc, const __bf16* __restrict__ wenc,
    const __bf16* __restrict__ venc,
    const float* __restrict__ q_b, const float* __restrict__ k_b,
    const float* __restrict__ gamma_q, const float* __restrict__ beta_q,
    const float* __restrict__ gamma_k, const float* __restrict__ beta_k,
    float* __restrict__ q_s, float* __restrict__ k_s, float* __restrict__ v_s)
{
    __shared__ __bf16 As[3][66][136];
    const int tid  = threadIdx.x;
    const int wave = tid >> 6;
    const int lane = tid & 63;
    const int m    = lane & 15;
    const int quad = lane >> 4;
    const int bx = blockIdx.x;
    const int b  = bx >> 5;
    const int lb0 = (bx & 31) << 6;
    const int yt = blockIdx.y;

    for (int e = tid; e < 3*66*16; e += 256) {
        const int p = e / (66*16), rem = e % (66*16);
        const int row = rem >> 4, cg = rem & 15;
        *(bf16x8*)&As[p][row][cg*8] =
            *(const bf16x8*)&xenc[((size_t)(p*2 + b)*XROWS + lb0 + row)*128 + cg*8];
    }
    __syncthreads();

    if (yt < 32) {
        const int o0 = yt << 6;
        const int osub = o0 + wave*16;
        float4v accm[4][4];
        float4v corr[4][2];
        #pragma unroll
        for (int lt = 0; lt < 4; ++lt) {
            corr[lt][0] = (float4v){0.f,0.f,0.f,0.f};
            corr[lt][1] = (float4v){0.f,0.f,0.f,0.f};
            #pragma unroll
            for (int c = 0; c < 4; ++c) accm[lt][c] = (float4v){0.f,0.f,0.f,0.f};
        }
        // B-frag double buffer over 12 rounds (cidx,t) = (idx/3, idx%3)
        bf16x8 Bb[2][3];
        {
            size_t base0 = ((size_t)0*2048 + osub + m)*128 + 0 + quad*8;
            Bb[0][0] = *(const bf16x8*)&wenc[base0];
            Bb[0][1] = *(const bf16x8*)&wenc[base0 + (size_t)3*2048*128];
            Bb[0][2] = *(const bf16x8*)&wenc[base0 + (size_t)6*2048*128];
        }
        #pragma unroll
        for (int idx = 0; idx < 12; ++idx) {
            const int cur = idx & 1, nxt = cur ^ 1;
            if (idx < 11) {
                const int nidx = idx + 1;
                const int nc0 = (nidx / 3) << 5, ntt = nidx % 3;
                size_t base = ((size_t)ntt*2048 + osub + m)*128 + nc0 + quad*8;
                Bb[nxt][0] = *(const bf16x8*)&wenc[base];
                Bb[nxt][1] = *(const bf16x8*)&wenc[base + (size_t)3*2048*128];
                Bb[nxt][2] = *(const bf16x8*)&wenc[base + (size_t)6*2048*128];
            }
            const int cidx = idx / 3, t = idx % 3;
            const int c0 = cidx << 5;
            #pragma unroll
            for (int lt = 0; lt < 4; ++lt) {
                const int row = lt*16 + m + t;
                bf16x8 A1 = *(const bf16x8*)&As[0][row][c0 + quad*8];
                bf16x8 A2 = *(const bf16x8*)&As[1][row][c0 + quad*8];
                bf16x8 A3 = *(const bf16x8*)&As[2][row][c0 + quad*8];
                accm[lt][cidx] = __builtin_amdgcn_mfma_f32_16x16x32_bf16(A1, Bb[cur][0], accm[lt][cidx], 0, 0, 0);
                corr[lt][0] = __builtin_amdgcn_mfma_f32_16x16x32_bf16(A1, Bb[cur][1], corr[lt][0], 0, 0, 0);
                corr[lt][1] = __builtin_amdgcn_mfma_f32_16x16x32_bf16(A2, Bb[cur][0], corr[lt][1], 0, 0, 0);
                corr[lt][0] = __builtin_amdgcn_mfma_f32_16x16x32_bf16(A1, Bb[cur][2], corr[lt][0], 0, 0, 0);
                corr[lt][1] = __builtin_amdgcn_mfma_f32_16x16x32_bf16(A3, Bb[cur][0], corr[lt][1], 0, 0, 0);
                corr[lt][0] = __builtin_amdgcn_mfma_f32_16x16x32_bf16(A2, Bb[cur][1], corr[lt][0], 0, 0, 0);
            }
        }
        const int is_k = (o0 >= 1024);
        const double g  = (double)(is_k ? gamma_k[0] : gamma_q[0]);
        const double be = (double)(is_k ? beta_k[0]  : beta_q[0]);
        const int o_global = osub + m;
        const int o_local  = o_global - (is_k ? 1024 : 0);
        const double bias  = (double)(is_k ? k_b[o_local] : q_b[o_local]);
        float* dest = is_k ? k_s : q_s;
        #pragma unroll
        for (int lt = 0; lt < 4; ++lt) {
            #pragma unroll
            for (int reg = 0; reg < 4; ++reg) {
                double s = (double)corr[lt][0][reg] + (double)corr[lt][1][reg];
                #pragma unroll
                for (int c = 0; c < 4; ++c) s += (double)accm[lt][c][reg];
                const int l = lb0 + lt*16 + quad*4 + reg;
                dest[((size_t)(b*LL + l))*OC + o_local] = (float)(g*(s + bias) + be);
            }
        }
    } else {
        const int o0 = (yt - 32) << 6;
        const int osub = o0 + wave*16;
        float4v accm[4][4];
        float4v corr[4];
        #pragma unroll
        for (int lt = 0; lt < 4; ++lt) {
            corr[lt] = (float4v){0.f,0.f,0.f,0.f};
            #pragma unroll
            for (int c = 0; c < 4; ++c) accm[lt][c] = (float4v){0.f,0.f,0.f,0.f};
        }
        bf16x8 Bb[2][2];
        {
            size_t base0 = ((size_t)(osub + m))*128 + 0 + quad*8;
            Bb[0][0] = *(const bf16x8*)&venc[base0];
            Bb[0][1] = *(const bf16x8*)&venc[base0 + (size_t)1024*128];
        }
        #pragma unroll
        for (int cidx = 0; cidx < 4; ++cidx) {
            const int cur = cidx & 1, nxt = cur ^ 1;
            if (cidx < 3) {
                size_t base = ((size_t)(osub + m))*128 + ((cidx+1) << 5) + quad*8;
                Bb[nxt][0] = *(const bf16x8*)&venc[base];
                Bb[nxt][1] = *(const bf16x8*)&venc[base + (size_t)1024*128];
            }
            const int c0 = cidx << 5;
            #pragma unroll
            for (int lt = 0; lt < 4; ++lt) {
                const int row = lt*16 + m + 2;
                bf16x8 A1 = *(const bf16x8*)&As[0][row][c0 + quad*8];
                bf16x8 A2 = *(const bf16x8*)&As[1][row][c0 + quad*8];
                accm[lt][cidx] = __builtin_amdgcn_mfma_f32_16x16x32_bf16(A1, Bb[cur][0], accm[lt][cidx], 0, 0, 0);
                corr[lt] = __builtin_amdgcn_mfma_f32_16x16x32_bf16(A1, Bb[cur][1], corr[lt], 0, 0, 0);
                corr[lt] = __builtin_amdgcn_mfma_f32_16x16x32_bf16(A2, Bb[cur][0], corr[lt], 0, 0, 0);
                corr[lt] = __builtin_amdgcn_mfma_f32_16x16x32_bf16(A2, Bb[cur][1], corr[lt], 0, 0, 0);
            }
        }
        const int o_local = osub + m;
        #pragma unroll
        for (int lt = 0; lt < 4; ++lt) {
            #pragma unroll
            for (int reg = 0; reg < 4; ++reg) {
                float s = corr[lt][reg];
                #pragma unroll
                for (int c = 0; c < 4; ++c) s += accm[lt][c][reg];
                const int l = lb0 + lt*16 + quad*4 + reg;
                v_s[((size_t)(b*LL + l))*OC + o_local] = s;
            }
        }
    }
}

// ---------------------------------------------------------------------------
// Kernel 2: sketch q+k fused, 3-plane/6-pass MFMA in-place; fast_phi epilogue.
// ---------------------------------------------------------------------------
__global__ __launch_bounds__(256) void sketch_mfma_k(
    float* __restrict__ q_s, float* __restrict__ k_s,
    const __bf16* __restrict__ genc_all)
{
    __shared__ __bf16 As[3][32][136];
    const int tid  = threadIdx.x;
    const int wave = tid >> 6;
    const int lane = tid & 63;
    const int m    = lane & 15;
    const int quad = lane >> 4;
    const int half = blockIdx.x >> 10;
    float* buf = half ? k_s : q_s;
    const __bf16* genc = genc_all + (size_t)half*2*3*128*128;
    const size_t i0 = (size_t)(blockIdx.x & 1023) * 32;

    for (int e = tid; e < 32*128; e += 256) {
        int row = e >> 7, d = e & 127;
        float v = buf[(i0 + row)*RR_ + d];
        __bf16 h1 = (__bf16)v;  float r1 = v - (float)h1;
        __bf16 h2 = (__bf16)r1; float r2 = r1 - (float)h2;
        __bf16 h3 = (__bf16)r2;
        As[0][row][d] = h1; As[1][row][d] = h2; As[2][row][d] = h3;
    }
    __syncthreads();

    float4v accm[2][2][2], corr[2][2][2];
    #pragma unroll
    for (int mt = 0; mt < 2; ++mt)
        #pragma unroll
        for (int nt = 0; nt < 2; ++nt)
            #pragma unroll
            for (int mat = 0; mat < 2; ++mat) {
                accm[mt][nt][mat] = (float4v){0.f,0.f,0.f,0.f};
                corr[mt][nt][mat] = (float4v){0.f,0.f,0.f,0.f};
            }

    #pragma unroll
    for (int ck = 0; ck < 4; ++ck) {
        const int k0 = ck << 5;
        bf16x8 A1[2], A2[2], A3[2];
        #pragma unroll
        for (int mt = 0; mt < 2; ++mt) {
            A1[mt] = *(const bf16x8*)&As[0][mt*16 + m][k0 + quad*8];
            A2[mt] = *(const bf16x8*)&As[1][mt*16 + m][k0 + quad*8];
            A3[mt] = *(const bf16x8*)&As[2][mt*16 + m][k0 + quad*8];
        }
        #pragma unroll
        for (int nt = 0; nt < 2; ++nt) {
            const int r = wave*32 + nt*16 + m;
            #pragma unroll
            for (int mat = 0; mat < 2; ++mat) {
                size_t base = ((size_t)(mat*3)*128 + r)*128 + k0 + quad*8;
                bf16x8 B1 = *(const bf16x8*)&genc[base];
                bf16x8 B2 = *(const bf16x8*)&genc[base + (size_t)128*128];
                bf16x8 B3 = *(const bf16x8*)&genc[base + (size_t)2*128*128];
                #pragma unroll
                for (int mt = 0; mt < 2; ++mt) {
                    accm[mt][nt][mat] = __builtin_amdgcn_mfma_f32_16x16x32_bf16(A1[mt], B1, accm[mt][nt][mat], 0, 0, 0);
                    corr[mt][nt][mat] = __builtin_amdgcn_mfma_f32_16x16x32_bf16(A1[mt], B2, corr[mt][nt][mat], 0, 0, 0);
                    corr[mt][nt][mat] = __builtin_amdgcn_mfma_f32_16x16x32_bf16(A2[mt], B1, corr[mt][nt][mat], 0, 0, 0);
                    corr[mt][nt][mat] = __builtin_amdgcn_mfma_f32_16x16x32_bf16(A1[mt], B3, corr[mt][nt][mat], 0, 0, 0);
                    corr[mt][nt][mat] = __builtin_amdgcn_mfma_f32_16x16x32_bf16(A3[mt], B1, corr[mt][nt][mat], 0, 0, 0);
                    corr[mt][nt][mat] = __builtin_amdgcn_mfma_f32_16x16x32_bf16(A2[mt], B2, corr[mt][nt][mat], 0, 0, 0);
                }
            }
        }
    }
    __syncthreads();

    #pragma unroll
    for (int mt = 0; mt < 2; ++mt)
        #pragma unroll
        for (int nt = 0; nt < 2; ++nt)
            #pragma unroll
            for (int reg = 0; reg < 4; ++reg) {
                double u1 = (double)accm[mt][nt][0][reg] + (double)corr[mt][nt][0][reg];
                double u2 = (double)accm[mt][nt][1][reg] + (double)corr[mt][nt][1][reg];
                const size_t row = i0 + mt*16 + quad*4 + reg;
                const int col = wave*32 + nt*16 + m;
                buf[row*RR_ + col] = fast_phi(u1, u2);
            }
}

// ---------------------------------------------------------------------------
// Kernel 3: KV^T partials via 2-plane MFMA + fp64 Ksum partials (r10-proven).
// ---------------------------------------------------------------------------
__global__ __launch_bounds__(512) void kv_mfma_k(
    const float* __restrict__ phi_k, const float* __restrict__ v,
    float* __restrict__ part_kv, double* __restrict__ part_ks)
{
    __shared__ float Pt[128*36];
    __shared__ float Vt[128*36];
    __shared__ double ksred[512];
    const int tid  = threadIdx.x;
    const int wave = tid >> 6;
    const int lane = tid & 63;
    const int m    = lane & 15;
    const int quad = lane >> 4;
    const int split = blockIdx.x;
    const int bh    = blockIdx.y;
    const int b = bh >> 3, h = bh & 7;
    const int lbase = split * 128;
    const int dh = wave & 1;
    const int rq = wave >> 1;

    float4v accm[4][2], corr[4][2];
    #pragma unroll
    for (int mt = 0; mt < 4; ++mt)
        #pragma unroll
        for (int nt = 0; nt < 2; ++nt) {
            accm[mt][nt] = (float4v){0.f,0.f,0.f,0.f};
            corr[mt][nt] = (float4v){0.f,0.f,0.f,0.f};
        }
    double ks = 0.0;

    for (int ch = 0; ch < 4; ++ch) {
        __syncthreads();
        for (int e = tid; e < 32*128; e += 512) {
            const int l = e >> 7, r = e & 127;
            size_t base = ((size_t)(b*LL + lbase + ch*32 + l)*HH + h)*RR_;
            float pv = phi_k[base + r];
            float vv = v[base + r];
            Pt[r*36 + l] = pv;
            Vt[r*36 + l] = vv;
            ks += (double)pv;
        }
        __syncthreads();
        bf16x8 A1[4], A2[4], B1[2], B2[2];
        #pragma unroll
        for (int mt = 0; mt < 4; ++mt)
            enc2(&Vt[(dh*64 + mt*16 + m)*36 + quad*8], A1[mt], A2[mt]);
        #pragma unroll
        for (int nt = 0; nt < 2; ++nt)
            enc2(&Pt[(rq*32 + nt*16 + m)*36 + quad*8], B1[nt], B2[nt]);
        #pragma unroll
        for (int mt = 0; mt < 4; ++mt)
            #pragma unroll
            for (int nt = 0; nt < 2; ++nt) {
                accm[mt][nt] = __builtin_amdgcn_mfma_f32_16x16x32_bf16(A1[mt], B1[nt], accm[mt][nt], 0, 0, 0);
                corr[mt][nt] = __builtin_amdgcn_mfma_f32_16x16x32_bf16(A1[mt], B2[nt], corr[mt][nt], 0, 0, 0);
                corr[mt][nt] = __builtin_amdgcn_mfma_f32_16x16x32_bf16(A2[mt], B1[nt], corr[mt][nt], 0, 0, 0);
                corr[mt][nt] = __builtin_amdgcn_mfma_f32_16x16x32_bf16(A2[mt], B2[nt], corr[mt][nt], 0, 0, 0);
            }
    }

    ksred[tid] = ks;
    __syncthreads();
    if (tid < 128) {
        double s = ksred[tid] + ksred[tid+128] + ksred[tid+256] + ksred[tid+384];
        part_ks[(bh*16 + split)*RR_ + tid] = s;
    }

    float* outp = part_kv + ((size_t)(bh*16 + split))*RR_*DD;
    #pragma unroll
    for (int mt = 0; mt < 4; ++mt)
        #pragma unroll
        for (int nt = 0; nt < 2; ++nt)
            #pragma unroll
            for (int reg = 0; reg < 4; ++reg) {
                const int d = dh*64 + mt*16 + quad*4 + reg;
                const int r = rq*32 + nt*16 + m;
                outp[d*128 + r] = accm[mt][nt][reg] + corr[mt][nt][reg];
            }
}

// ---------------------------------------------------------------------------
// Kernel 4: reduce KVT partials -> bf16 2-plane KVTenc.
// ---------------------------------------------------------------------------
__global__ __launch_bounds__(256) void kvreduce_k(
    const float* __restrict__ part_kv, __bf16* __restrict__ kvt_enc)
{
    const int gid = blockIdx.x*256 + threadIdx.x;
    if (gid >= 16*RR_*DD) return;
    const int bh = gid >> 14;
    const int rd = gid & 16383;
    float s = 0.f;
    #pragma unroll
    for (int c = 0; c < 16; ++c)
        s += part_kv[(((size_t)(bh*16 + c)) << 14) + rd];
    __bf16 h1 = (__bf16)s;
    __bf16 h2 = (__bf16)(s - (float)h1);
    kvt_enc[(size_t)bh*16384 + rd] = h1;
    kvt_enc[(size_t)(16 + bh)*16384 + rd] = h2;
}

// ---------------------------------------------------------------------------
// Kernel 5: numerator MFMA + fp64 den (r10-proven).
// ---------------------------------------------------------------------------
__global__ __launch_bounds__(256) void numden_mfma_k(
    const float* __restrict__ phi_q, const __bf16* __restrict__ kvt_enc,
    const double* __restrict__ part_ks, float* __restrict__ o_out)
{
    __shared__ float Pq[64*132];
    __shared__ double Ks_s[128];
    __shared__ double den_s[64];
    const int tid  = threadIdx.x;
    const int wave = tid >> 6;
    const int lane = tid & 63;
    const int m    = lane & 15;
    const int quad = lane >> 4;
    const int lt = blockIdx.x;
    const int bh = blockIdx.y;
    const int b = bh >> 3, h = bh & 7;
    const int l0 = lt * 64;

    if (tid < 128) {
        double s = 0.0;
        #pragma unroll
        for (int c = 0; c < 16; ++c) s += part_ks[(bh*16 + c)*RR_ + tid];
        Ks_s[tid] = s;
    }
    for (int e = tid; e < 64*128; e += 256) {
        const int l = e >> 7, r = e & 127;
        Pq[l*132 + r] = phi_q[((size_t)(b*LL + l0 + l)*HH + h)*RR_ + r];
    }
    __syncthreads();

    double den = 0.0;
    if (tid < 64) {
        #pragma unroll
        for (int r = 0; r < 128; ++r)
            den += (double)Pq[tid*132 + r] * Ks_s[r];
    }

    float4v accm[4][2], corr[4][2];
    #pragma unroll
    for (int mt = 0; mt < 4; ++mt)
        #pragma unroll
        for (int nt = 0; nt < 2; ++nt) {
            accm[mt][nt] = (float4v){0.f,0.f,0.f,0.f};
            corr[mt][nt] = (float4v){0.f,0.f,0.f,0.f};
        }

    #pragma unroll
    for (int ck = 0; ck < 4; ++ck) {
        const int k0 = ck << 5;
        bf16x8 A1[4], A2[4];
        #pragma unroll
        for (int mt = 0; mt < 4; ++mt)
            enc2(&Pq[(mt*16 + m)*132 + k0 + quad*8], A1[mt], A2[mt]);
        #pragma unroll
        for (int nt = 0; nt < 2; ++nt) {
            const int d = wave*32 + nt*16 + m;
            size_t base = ((size_t)bh*128 + d)*128 + k0 + quad*8;
            bf16x8 B1 = *(const bf16x8*)&kvt_enc[base];
            bf16x8 B2 = *(const bf16x8*)&kvt_enc[base + (size_t)16*16384];
            #pragma unroll
            for (int mt = 0; mt < 4; ++mt) {
                accm[mt][nt] = __builtin_amdgcn_mfma_f32_16x16x32_bf16(A1[mt], B1, accm[mt][nt], 0, 0, 0);
                corr[mt][nt] = __builtin_amdgcn_mfma_f32_16x16x32_bf16(A1[mt], B2, corr[mt][nt], 0, 0, 0);
                corr[mt][nt] = __builtin_amdgcn_mfma_f32_16x16x32_bf16(A2[mt], B1, corr[mt][nt], 0, 0, 0);
                corr[mt][nt] = __builtin_amdgcn_mfma_f32_16x16x32_bf16(A2[mt], B2, corr[mt][nt], 0, 0, 0);
            }
        }
    }

    __syncthreads();
    if (tid < 64) den_s[tid] = den;
    __syncthreads();

    #pragma unroll
    for (int mt = 0; mt < 4; ++mt)
        #pragma unroll
        for (int nt = 0; nt < 2; ++nt)
            #pragma unroll
            for (int reg = 0; reg < 4; ++reg) {
                const int ll = mt*16 + quad*4 + reg;
                const int d  = wave*32 + nt*16 + m;
                const float inv = (float)(1.0 / (den_s[ll] + 1e-6));
                o_out[((size_t)(b*LL + l0 + ll))*OC + h*DD + d] =
                    (accm[mt][nt][reg] + corr[mt][nt][reg]) * inv;
            }
}

// ---------------------------------------------------------------------------
// Kernel 6: output projection partials via 2-plane MFMA (r10-proven).
// ---------------------------------------------------------------------------
__global__ __launch_bounds__(256) void proj_part_mfma_k(
    const float* __restrict__ o_s, const __bf16* __restrict__ penc,
    float* __restrict__ part)
{
    __shared__ float As[32*260];
    const int tid  = threadIdx.x;
    const int wave = tid >> 6;
    const int lane = tid & 63;
    const int m    = lane & 15;
    const int quad = lane >> 4;
    const int row0  = blockIdx.x * 32;
    const int kbase = blockIdx.y * 256;

    for (int e = tid; e < 32*256; e += 256) {
        const int row = e >> 8, k = e & 255;
        As[row*260 + k] = o_s[(size_t)(row0 + row)*OC + kbase + k];
    }
    __syncthreads();

    float4v accm[2][2], corr[2][2];
    #pragma unroll
    for (int mt = 0; mt < 2; ++mt)
        #pragma unroll
        for (int nt = 0; nt < 2; ++nt) {
            accm[mt][nt] = (float4v){0.f,0.f,0.f,0.f};
            corr[mt][nt] = (float4v){0.f,0.f,0.f,0.f};
        }

    #pragma unroll
    for (int ck = 0; ck < 8; ++ck) {
        const int k0 = ck << 5;
        bf16x8 A1[2], A2[2];
        #pragma unroll
        for (int mt = 0; mt < 2; ++mt)
            enc2(&As[(mt*16 + m)*260 + k0 + quad*8], A1[mt], A2[mt]);
        #pragma unroll
        for (int nt = 0; nt < 2; ++nt) {
            const int j = wave*32 + nt*16 + m;
            size_t base = ((size_t)j)*OC + kbase + k0 + quad*8;
            bf16x8 B1 = *(const bf16x8*)&penc[base];
            bf16x8 B2 = *(const bf16x8*)&penc[base + (size_t)128*OC];
            #pragma unroll
            for (int mt = 0; mt < 2; ++mt) {
                accm[mt][nt] = __builtin_amdgcn_mfma_f32_16x16x32_bf16(A1[mt], B1, accm[mt][nt], 0, 0, 0);
                corr[mt][nt] = __builtin_amdgcn_mfma_f32_16x16x32_bf16(A1[mt], B2, corr[mt][nt], 0, 0, 0);
                corr[mt][nt] = __builtin_amdgcn_mfma_f32_16x16x32_bf16(A2[mt], B1, corr[mt][nt], 0, 0, 0);
                corr[mt][nt] = __builtin_amdgcn_mfma_f32_16x16x32_bf16(A2[mt], B2, corr[mt][nt], 0, 0, 0);
            }
        }
    }

    float* outp = part + (size_t)blockIdx.y*BL*DD;
    #pragma unroll
    for (int mt = 0; mt < 2; ++mt)
        #pragma unroll
        for (int nt = 0; nt < 2; ++nt)
            #pragma unroll
            for (int reg = 0; reg < 4; ++reg) {
                const int row = row0 + mt*16 + quad*4 + reg;
                const int j   = wave*32 + nt*16 + m;
                outp[(size_t)row*DD + j] = accm[mt][nt][reg] + corr[mt][nt][reg];
            }
}

// ---------------------------------------------------------------------------
// Kernel 7: reduce the 4 K-split partials + bias.
// ---------------------------------------------------------------------------
__global__ __launch_bounds__(256) void proj_reduce_k(
    const float* __restrict__ part, const float* __restrict__ pb,
    float* __restrict__ out)
{
    const int gid = blockIdx.x*256 + threadIdx.x;
    if (gid >= BL*DD/4) return;
    const float4* p4 = (const float4*)part;
    float4 s = p4[gid];
    #pragma unroll
    for (int c = 1; c < 4; ++c) {
        float4 t = p4[gid + (size_t)c*(BL*DD/4)];
        s.x += t.x; s.y += t.y; s.z += t.z; s.w += t.w;
    }
    const int col = (gid << 2) & (DD-1);
    s.x += pb[col]; s.y += pb[col+1]; s.z += pb[col+2]; s.w += pb[col+3];
    ((float4*)out)[gid] = s;
}

// ---------------------------------------------------------------------------
extern "C" void kernel_launch(void* const* d_in, const int* in_sizes, int n_in,
                              void* d_out, int out_size, void* d_ws, size_t ws_size,
                              hipStream_t stream) {
    const float* x       = (const float*)d_in[0];
    const float* q_w     = (const float*)d_in[1];
    const float* q_b     = (const float*)d_in[2];
    const float* k_w     = (const float*)d_in[3];
    const float* k_b     = (const float*)d_in[4];
    const float* v_w     = (const float*)d_in[5];
    const float* g1_q    = (const float*)d_in[6];
    const float* g2_q    = (const float*)d_in[7];
    const float* g1_k    = (const float*)d_in[8];
    const float* g2_k    = (const float*)d_in[9];
    const float* gamma_q = (const float*)d_in[10];
    const float* beta_q  = (const float*)d_in[11];
    const float* gamma_k = (const float*)d_in[12];
    const float* beta_k  = (const float*)d_in[13];
    const float* proj_w  = (const float*)d_in[14];
    const float* proj_b  = (const float*)d_in[15];

    float* f = (float*)d_ws;
    float* q_s     = f;                        // 4,194,304 floats
    float* k_s     = f + 4194304;              // 4,194,304
    float* v_s     = f + 8388608;              // 4,194,304
    float* part_kv = f + 12582912;             // 4,194,304 (scratch: wenc/xenc/kv parts/proj parts)
    double* part_ks = (double*)(f + 16777216); // 32,768 doubles
    __bf16* kvt_enc = (__bf16*)(f + 16842752); // 524,288 bf16
    __bf16* genc   = (__bf16*)(f + 17104896);  // 196,608 bf16
    __bf16* venc   = (__bf16*)(f + 17203200);  // 262,144 bf16
    __bf16* penc   = (__bf16*)(f + 17334272);  // 262,144 bf16
    float* o_s     = k_s;                      // reuse (phi_k dead after kv_mfma)
    float* proj_part = part_kv;                // reuse (kv parts dead after kvreduce)
    __bf16* wenc   = (__bf16*)(f + 12582912);
    __bf16* xenc   = (__bf16*)(f + 13762560);

    dim3 blk(256);
    enc_fused_k<<<2816, blk, 0, stream>>>(q_w, k_w, v_w, proj_w,
                                          g1_q, g2_q, g1_k, g2_k, x,
                                          wenc, genc, venc, penc, xenc);
    conv_mfma_k<<<dim3(64,48), blk, 0, stream>>>(xenc, wenc, venc, q_b, k_b,
                                                 gamma_q, beta_q, gamma_k, beta_k,
                                                 q_s, k_s, v_s);
    sketch_mfma_k<<<2048, blk, 0, stream>>>(q_s, k_s, genc);
    kv_mfma_k<<<dim3(16,16), dim3(512), 0, stream>>>(k_s, v_s, part_kv, part_ks);
    kvreduce_k<<<1024, blk, 0, stream>>>(part_kv, kvt_enc);
    numden_mfma_k<<<dim3(32,16), blk, 0, stream>>>(q_s, kvt_enc, part_ks, o_s);
    proj_part_mfma_k<<<dim3(128,4), blk, 0, stream>>>(o_s, penc, proj_part);
    proj_reduce_k<<<512, blk, 0, stream>>>(proj_part, proj_b, (float*)d_out);
}